// Round 1
// baseline (9245.969 us; speedup 1.0000x reference)
//
#include <hip/hip_runtime.h>

#define CONV_ACC  1
#define CONV_RELU 2

// ---------------- transpose (l,c,d,h,w) -> token-major [n=(l,d,h,w), c] ----------------
__global__ __launch_bounds__(256) void k_transpose_in(const float* __restrict__ x,
                                                      float* __restrict__ xt) {
  int idx = blockIdx.x * 256 + threadIdx.x;   // over N*C, c fastest
  int c = idx & 127;
  int n = idx >> 7;
  int l = n >> 12;
  int s = n & 4095;
  xt[idx] = x[((l * 128 + c) << 12) + s];
}

__global__ __launch_bounds__(256) void k_transpose_out(const float* __restrict__ xt,
                                                       float* __restrict__ out) {
  int idx = blockIdx.x * 256 + threadIdx.x;   // output layout (l,c,s), s fastest
  int s = idx & 4095;
  int c = (idx >> 12) & 127;
  int l = idx >> 19;
  out[idx] = xt[(((l << 12) | s) << 7) + c];
}

// ---------------- layernorm over 128 channels, one wave per row ----------------
__global__ __launch_bounds__(256) void k_layernorm(const float* __restrict__ X,
                                                   const float* __restrict__ g,
                                                   const float* __restrict__ b,
                                                   float* __restrict__ Y, int M) {
  int n = blockIdx.x * 4 + (threadIdx.x >> 6);
  if (n >= M) return;
  int lane = threadIdx.x & 63;
  const float* row = X + (long)n * 128;
  float2 v = *(const float2*)(row + lane * 2);
  float s = v.x + v.y;
#pragma unroll
  for (int o = 32; o > 0; o >>= 1) s += __shfl_xor(s, o);
  float mu = s * (1.0f / 128.0f);
  float dx = v.x - mu, dy = v.y - mu;
  float q = dx * dx + dy * dy;
#pragma unroll
  for (int o = 32; o > 0; o >>= 1) q += __shfl_xor(q, o);
  float rs = rsqrtf(q * (1.0f / 128.0f) + 1e-5f);
  float2 gv = *(const float2*)(g + lane * 2);
  float2 bv = *(const float2*)(b + lane * 2);
  float2 o2;
  o2.x = dx * rs * gv.x + bv.x;
  o2.y = dy * rs * gv.y + bv.y;
  *(float2*)(Y + (long)n * 128 + lane * 2) = o2;
}

// ---------------- weight repack: W[oc][ic][tap] -> W2[tap][ic][oc] ----------------
__global__ __launch_bounds__(256) void k_repack(const float* __restrict__ W,
                                                float* __restrict__ W2,
                                                int OC, int IC, int NT) {
  long idx = (long)blockIdx.x * 256 + threadIdx.x;
  if (idx >= (long)OC * IC * NT) return;
  int oc = (int)(idx % OC);
  long r = idx / OC;
  int ic = (int)(r % IC);
  int t = (int)(r / IC);
  W2[idx] = W[((long)oc * IC + ic) * NT + t];
}

// ---------------- generic conv-as-gather-GEMM ----------------
// mode 0: 3x1x1x1 conv along L, half-local padding (tlg). NT=3
// mode 1: 1x3x3x3 conv over (d,h,w), optional stride.        NT=27
// mode 2: 3x3x3x3 conv over (l,d,h,w).                       NT=81
// Out tile: 64 tokens x 64 ocs; block 256 threads; 4x4 acc per thread.
__global__ __launch_bounds__(256) void k_conv(
    const float* __restrict__ X, const float* __restrict__ W2,
    const float* __restrict__ bias, float* __restrict__ Y,
    int M, int IC, int OC, int mode,
    int Do, int Ho, int Wo,
    int Li, int Di, int Hi, int Wi,
    int sL, int sD, int sH, int sW, int flags) {
  __shared__ float As[32][64];   // As[k][token]
  __shared__ float Bs[32][64];   // Bs[k][oc]
  __shared__ int nbr[64];
  int tid = threadIdx.x;
  int m0 = blockIdx.x * 64;
  int oc0 = blockIdx.y * 64;
  int NT = (mode == 0) ? 3 : (mode == 1 ? 27 : 81);
  float acc[4][4] = {{0.f}};
  int ty = tid >> 4, tx = tid & 15;

  for (int tap = 0; tap < NT; ++tap) {
    if (tid < 64) {
      int m = m0 + tid;
      int nb = -1;
      if (m < M) {
        int w = m % Wo, h = (m / Wo) % Ho, d = (m / (Wo * Ho)) % Do, l = m / (Wo * Ho * Do);
        int li, di, hi, wi;
        bool ok = true;
        if (mode == 0) {
          int dl = tap - 1;
          int ll = (l & 1) + dl;
          ok = (ll >= 0 && ll < 2);
          li = l + dl; di = d; hi = h; wi = w;
        } else if (mode == 1) {
          li = l * sL;
          di = d * sD + tap / 9 - 1;
          hi = h * sH + (tap / 3) % 3 - 1;
          wi = w * sW + tap % 3 - 1;
          ok = (di >= 0 && di < Di && hi >= 0 && hi < Hi && wi >= 0 && wi < Wi);
        } else {
          li = l + tap / 27 - 1;
          di = d + (tap / 9) % 3 - 1;
          hi = h + (tap / 3) % 3 - 1;
          wi = w + tap % 3 - 1;
          ok = (li >= 0 && li < Li && di >= 0 && di < Di && hi >= 0 && hi < Hi &&
                wi >= 0 && wi < Wi);
        }
        if (ok) nb = ((li * Di + di) * Hi + hi) * Wi + wi;
      }
      nbr[tid] = nb;
    }
    __syncthreads();
    for (int k0 = 0; k0 < IC; k0 += 32) {
      {  // stage A (transposed): rows = tokens
        int r = tid >> 2, q = (tid & 3) << 3;
        int nb = nbr[r];
        float4 v0 = make_float4(0.f, 0.f, 0.f, 0.f), v1 = v0;
        if (nb >= 0) {
          const float* src = X + (long)nb * IC + k0 + q;
          v0 = *(const float4*)src;
          v1 = *(const float4*)(src + 4);
        }
        As[q + 0][r] = v0.x; As[q + 1][r] = v0.y; As[q + 2][r] = v0.z; As[q + 3][r] = v0.w;
        As[q + 4][r] = v1.x; As[q + 5][r] = v1.y; As[q + 6][r] = v1.z; As[q + 7][r] = v1.w;
      }
      {  // stage B: W2[tap][ic][oc], coalesced
        int kr = tid >> 4, o4 = (tid & 15) << 2;
        const float* wp = W2 + ((long)tap * IC + k0 + kr) * OC + oc0 + o4;
        *(float4*)&Bs[kr][o4] = *(const float4*)wp;
        *(float4*)&Bs[kr + 16][o4] = *(const float4*)(wp + (long)16 * OC);
      }
      __syncthreads();
#pragma unroll
      for (int kk = 0; kk < 32; ++kk) {
        float4 av = *(const float4*)&As[kk][ty << 2];
        float4 bv = *(const float4*)&Bs[kk][tx << 2];
        acc[0][0] += av.x * bv.x; acc[0][1] += av.x * bv.y; acc[0][2] += av.x * bv.z; acc[0][3] += av.x * bv.w;
        acc[1][0] += av.y * bv.x; acc[1][1] += av.y * bv.y; acc[1][2] += av.y * bv.z; acc[1][3] += av.y * bv.w;
        acc[2][0] += av.z * bv.x; acc[2][1] += av.z * bv.y; acc[2][2] += av.z * bv.z; acc[2][3] += av.z * bv.w;
        acc[3][0] += av.w * bv.x; acc[3][1] += av.w * bv.y; acc[3][2] += av.w * bv.z; acc[3][3] += av.w * bv.w;
      }
      __syncthreads();
    }
  }
#pragma unroll
  for (int i = 0; i < 4; ++i) {
    int m = m0 + (ty << 2) + i;
    if (m >= M) continue;
    float* yp = Y + (long)m * OC + oc0 + (tx << 2);
    const float* bp = bias + oc0 + (tx << 2);
#pragma unroll
    for (int j = 0; j < 4; ++j) {
      float v = acc[i][j] + bp[j];
      if (flags & CONV_RELU) v = fmaxf(v, 0.f);
      if (flags & CONV_ACC) v += yp[j];
      yp[j] = v;
    }
  }
}

// ---------------- TLG windowed cross attention: 8q x 8k per (window, head) ----------------
// lane = i*8 + j ; i = query idx in window, j = key idx.
__global__ __launch_bounds__(256) void k_tlg_attn(const float* __restrict__ Q,
                                                  const float* __restrict__ K,
                                                  const float* __restrict__ V,
                                                  float* __restrict__ Y) {
  int gw = blockIdx.x * 4 + (threadIdx.x >> 6);  // 0..16383 = 2048 windows * 8 heads
  int lane = threadIdx.x & 63;
  int head = gw & 7;
  int win = gw >> 3;
  int wB = win & 7, hB = (win >> 3) & 7, dB = (win >> 6) & 7, l = win >> 9;  // l global 0..3
  int i = lane >> 3, j = lane & 7;
  int nq = (l << 12) | ((dB * 2 + (i >> 2)) << 8) | ((hB * 2 + ((i >> 1) & 1)) << 4) |
           (wB * 2 + (i & 1));
  int lk = l ^ 2;  // other half
  int nk = (lk << 12) | ((dB * 2 + (j >> 2)) << 8) | ((hB * 2 + ((j >> 1) & 1)) << 4) |
           (wB * 2 + (j & 1));
  int hoff = head * 16;
  const float* qp = Q + (long)nq * 128 + hoff;
  const float* kp = K + (long)nk * 128 + hoff;
  float s = 0.f;
#pragma unroll
  for (int t = 0; t < 4; ++t) {
    float4 a = *(const float4*)(qp + t * 4);
    float4 b = *(const float4*)(kp + t * 4);
    s += a.x * b.x + a.y * b.y + a.z * b.z + a.w * b.w;
  }
  s *= 0.25f;  // HEAD_DIM^-0.5
  float mx = s;
#pragma unroll
  for (int o = 1; o < 8; o <<= 1) mx = fmaxf(mx, __shfl_xor(mx, o));
  float e = __expf(s - mx);
  float sum = e;
#pragma unroll
  for (int o = 1; o < 8; o <<= 1) sum += __shfl_xor(sum, o);
  float p = e / sum;
  const float* vp = V + (long)nk * 128 + hoff;
  float y[16];
#pragma unroll
  for (int t = 0; t < 16; t += 4) {
    float4 vv = *(const float4*)(vp + t);
    y[t] = p * vv.x; y[t + 1] = p * vv.y; y[t + 2] = p * vv.z; y[t + 3] = p * vv.w;
  }
#pragma unroll
  for (int o = 1; o < 8; o <<= 1) {
#pragma unroll
    for (int t = 0; t < 16; ++t) y[t] += __shfl_xor(y[t], o);
  }
  if (j == 0) {
    float* yp = Y + (long)nq * 128 + hoff;
#pragma unroll
    for (int t = 0; t < 16; t += 4) {
      float4 o4 = {y[t], y[t + 1], y[t + 2], y[t + 3]};
      *(float4*)(yp + t) = o4;
    }
  }
}

// ---------------- SLG global attention: one wave per (query, head); NK keys ----------------
__global__ __launch_bounds__(256) void k_slg_attn(const float* __restrict__ Q,
                                                  const float* __restrict__ K,
                                                  const float* __restrict__ V,
                                                  float* __restrict__ Y, int NK) {
  int gw = blockIdx.x * 4 + (threadIdx.x >> 6);  // 0..131071
  int lane = threadIdx.x & 63;
  int head = gw & 7;
  int nq = gw >> 3;
  int hoff = head * 16;
  const float* qp = Q + (long)nq * 128 + hoff;
  float qv[16];
#pragma unroll
  for (int t = 0; t < 16; t += 4) {
    float4 a = *(const float4*)(qp + t);
    qv[t] = a.x; qv[t + 1] = a.y; qv[t + 2] = a.z; qv[t + 3] = a.w;
  }
  float sc[17];
  float smax = -1e30f;
#pragma unroll
  for (int cc = 0; cc < 17; ++cc) {
    int k = lane + cc * 64;
    float s = -1e30f;
    if (k < NK) {
      const float* kp = K + (long)k * 128 + hoff;
      float s0 = 0.f;
#pragma unroll
      for (int t = 0; t < 16; t += 4) {
        float4 b = *(const float4*)(kp + t);
        s0 += qv[t] * b.x + qv[t + 1] * b.y + qv[t + 2] * b.z + qv[t + 3] * b.w;
      }
      s = s0 * 0.25f;
    }
    sc[cc] = s;
    smax = fmaxf(smax, s);
  }
#pragma unroll
  for (int o = 32; o > 0; o >>= 1) smax = fmaxf(smax, __shfl_xor(smax, o));
  float y[16] = {0.f};
  float sum = 0.f;
#pragma unroll
  for (int cc = 0; cc < 17; ++cc) {
    int k = lane + cc * 64;
    if (k < NK) {
      float p = __expf(sc[cc] - smax);
      sum += p;
      const float* vp = V + (long)k * 128 + hoff;
#pragma unroll
      for (int t = 0; t < 16; t += 4) {
        float4 vv = *(const float4*)(vp + t);
        y[t] += p * vv.x; y[t + 1] += p * vv.y; y[t + 2] += p * vv.z; y[t + 3] += p * vv.w;
      }
    }
  }
#pragma unroll
  for (int o = 32; o > 0; o >>= 1) sum += __shfl_xor(sum, o);
#pragma unroll
  for (int o = 32; o > 0; o >>= 1) {
#pragma unroll
    for (int t = 0; t < 16; ++t) y[t] += __shfl_xor(y[t], o);
  }
  if (lane == 0) {
    float inv = 1.0f / sum;
    float* yp = Y + (long)nq * 128 + hoff;
#pragma unroll
    for (int t = 0; t < 16; t += 4) {
      float4 o4 = {y[t] * inv, y[t + 1] * inv, y[t + 2] * inv, y[t + 3] * inv};
      *(float4*)(yp + t) = o4;
    }
  }
}

extern "C" void kernel_launch(void* const* d_in, const int* in_sizes, int n_in,
                              void* d_out, int out_size, void* d_ws, size_t ws_size,
                              hipStream_t stream) {
  (void)in_sizes; (void)n_in; (void)out_size; (void)ws_size;
  const float* x    = (const float*)d_in[0];
  const float* n1_w = (const float*)d_in[1];  const float* n1_b = (const float*)d_in[2];
  const float* n2_w = (const float*)d_in[3];  const float* n2_b = (const float*)d_in[4];
  const float* n3_w = (const float*)d_in[5];  const float* n3_b = (const float*)d_in[6];
  const float* sn_w = (const float*)d_in[7];  const float* sn_b = (const float*)d_in[8];
  const float* tq_w = (const float*)d_in[9];  const float* tq_b = (const float*)d_in[10];
  const float* tk_w = (const float*)d_in[11]; const float* tk_b = (const float*)d_in[12];
  const float* tv_w = (const float*)d_in[13]; const float* tv_b = (const float*)d_in[14];
  const float* tp_w = (const float*)d_in[15]; const float* tp_b = (const float*)d_in[16];
  const float* sq_w = (const float*)d_in[17]; const float* sq_b = (const float*)d_in[18];
  const float* sk_w = (const float*)d_in[19]; const float* sk_b = (const float*)d_in[20];
  const float* sv_w = (const float*)d_in[21]; const float* sv_b = (const float*)d_in[22];
  const float* sp_w = (const float*)d_in[23]; const float* sp_b = (const float*)d_in[24];
  const float* sf_w = (const float*)d_in[25]; const float* sf_b = (const float*)d_in[26];
  const float* sc_w = (const float*)d_in[27]; const float* sc_b = (const float*)d_in[28];
  const float* m1_w = (const float*)d_in[29]; const float* m1_b = (const float*)d_in[30];
  const float* m2_w = (const float*)d_in[31]; const float* m2_b = (const float*)d_in[32];

  float* ws = (float*)d_ws;
  const long NC = 2097152L;  // 16384 * 128
  float* X0 = ws;
  float* XN = ws + NC;
  float* Qb = ws + 2 * NC;
  float* Kb = ws + 3 * NC;
  float* Vb = ws + 4 * NC;
  float* Yb = ws + 5 * NC;
  float* XC = ws + 6 * NC;          // 8 * 128
  float* XF = XC + 1024;            // 1024 * 128
  float* wp0 = XF + 131072;
  float* tq2 = wp0;
  float* tk2 = tq2 + 49152;  float* tv2 = tk2 + 49152;  float* tp2 = tv2 + 49152;
  float* sq2 = tp2 + 49152;
  float* sk2 = sq2 + 442368; float* sv2 = sk2 + 442368; float* sp2 = sv2 + 442368;
  float* sf2 = sp2 + 442368; float* sc2 = sf2 + 442368;
  float* m12 = sc2 + 442368;
  float* m22 = m12 + 5308416L;
  float* H4 = Qb;  // [16384,512] aliases Q..Y (all dead during MLP)

  auto rp = [&](const float* W, float* W2, int OC, int IC, int NT) {
    long tot = (long)OC * IC * NT;
    k_repack<<<(int)((tot + 255) / 256), 256, 0, stream>>>(W, W2, OC, IC, NT);
  };
  rp(tq_w, tq2, 128, 128, 3);  rp(tk_w, tk2, 128, 128, 3);
  rp(tv_w, tv2, 128, 128, 3);  rp(tp_w, tp2, 128, 128, 3);
  rp(sq_w, sq2, 128, 128, 27); rp(sk_w, sk2, 128, 128, 27);
  rp(sv_w, sv2, 128, 128, 27); rp(sp_w, sp2, 128, 128, 27);
  rp(sf_w, sf2, 128, 128, 27); rp(sc_w, sc2, 128, 128, 27);
  rp(m1_w, m12, 512, 128, 81); rp(m2_w, m22, 128, 512, 81);

  auto conv = [&](const float* Xp, const float* W2p, const float* Bp, float* Yp,
                  int M, int IC, int OC, int mode,
                  int Do, int Ho, int Wo, int Li, int Di, int Hi, int Wi,
                  int sL, int sD, int sH, int sW, int flags) {
    dim3 g((M + 63) / 64, OC / 64);
    k_conv<<<g, 256, 0, stream>>>(Xp, W2p, Bp, Yp, M, IC, OC, mode,
                                  Do, Ho, Wo, Li, Di, Hi, Wi, sL, sD, sH, sW, flags);
  };

  k_transpose_in<<<8192, 256, 0, stream>>>(x, X0);

  // ---- TLG branch ----
  k_layernorm<<<4096, 256, 0, stream>>>(X0, n1_w, n1_b, XN, 16384);
  conv(XN, tq2, tq_b, Qb, 16384, 128, 128, 0, 16, 16, 16, 4, 16, 16, 16, 1, 1, 1, 1, 0);
  conv(XN, tk2, tk_b, Kb, 16384, 128, 128, 0, 16, 16, 16, 4, 16, 16, 16, 1, 1, 1, 1, 0);
  conv(XN, tv2, tv_b, Vb, 16384, 128, 128, 0, 16, 16, 16, 4, 16, 16, 16, 1, 1, 1, 1, 0);
  k_tlg_attn<<<4096, 256, 0, stream>>>(Qb, Kb, Vb, Yb);
  conv(Yb, tp2, tp_b, X0, 16384, 128, 128, 0, 16, 16, 16, 4, 16, 16, 16, 1, 1, 1, 1, CONV_ACC);

  // ---- SLG branch ----
  k_layernorm<<<4096, 256, 0, stream>>>(X0, n2_w, n2_b, XN, 16384);
  conv(XN, sq2, sq_b, Qb, 16384, 128, 128, 1, 16, 16, 16, 4, 16, 16, 16, 1, 1, 1, 1, 0);
  conv(XN, sc2, sc_b, XC, 8,    128, 128, 1, 2, 2, 2,   4, 16, 16, 16, 4, 8, 8, 8, 0);
  conv(XN, sf2, sf_b, XF, 1024, 128, 128, 1, 8, 8, 8,   4, 16, 16, 16, 2, 2, 2, 2, 0);
  conv(XC, sk2, sk_b, Kb,            8,    128, 128, 1, 2, 2, 2, 1, 2, 2, 2, 1, 1, 1, 1, 0);
  conv(XF, sk2, sk_b, Kb + 8 * 128,  1024, 128, 128, 1, 8, 8, 8, 2, 8, 8, 8, 1, 1, 1, 1, 0);
  conv(XC, sv2, sv_b, Vb,            8,    128, 128, 1, 2, 2, 2, 1, 2, 2, 2, 1, 1, 1, 1, 0);
  conv(XF, sv2, sv_b, Vb + 8 * 128,  1024, 128, 128, 1, 8, 8, 8, 2, 8, 8, 8, 1, 1, 1, 1, 0);
  k_layernorm<<<258, 256, 0, stream>>>(Kb, sn_w, sn_b, Kb, 1032);
  k_layernorm<<<258, 256, 0, stream>>>(Vb, sn_w, sn_b, Vb, 1032);
  k_slg_attn<<<32768, 256, 0, stream>>>(Qb, Kb, Vb, Yb, 1032);
  conv(Yb, sp2, sp_b, X0, 16384, 128, 128, 1, 16, 16, 16, 4, 16, 16, 16, 1, 1, 1, 1, CONV_ACC);

  // ---- MLP branch ----
  k_layernorm<<<4096, 256, 0, stream>>>(X0, n3_w, n3_b, XN, 16384);
  conv(XN, m12, m1_b, H4, 16384, 128, 512, 2, 16, 16, 16, 4, 16, 16, 16, 1, 1, 1, 1, CONV_RELU);
  conv(H4, m22, m2_b, X0, 16384, 512, 128, 2, 16, 16, 16, 4, 16, 16, 16, 1, 1, 1, 1, CONV_ACC);

  k_transpose_out<<<8192, 256, 0, stream>>>(X0, (float*)d_out);
}

// Round 2
// 2528.333 us; speedup vs baseline: 3.6569x; 3.6569x over previous
//
#include <hip/hip_runtime.h>

typedef unsigned short u16;
typedef __attribute__((ext_vector_type(8))) short bf16x8;
typedef __attribute__((ext_vector_type(4))) float f32x4;

#define PITCH 40  // shorts per LDS row (80B): 8 rows cover all 32 banks, 2-way free

__device__ __forceinline__ u16 f2bf(float f) {
  union { float f; unsigned u; } v; v.f = f;
  unsigned r = v.u + 0x7fffu + ((v.u >> 16) & 1u);
  return (u16)(r >> 16);
}
__device__ __forceinline__ float bf2f(u16 h) {
  union { unsigned u; float f; } v; v.u = ((unsigned)h) << 16;
  return v.f;
}
__device__ __forceinline__ float4 load4bf(const u16* p) {
  ushort4 h = *(const ushort4*)p;
  return make_float4(bf2f(h.x), bf2f(h.y), bf2f(h.z), bf2f(h.w));
}

// ---------------- transpose (l,c,d,h,w) -> token-major [n=(l,d,h,w), c] fp32 ----------------
__global__ __launch_bounds__(256) void k_transpose_in(const float* __restrict__ x,
                                                      float* __restrict__ xt) {
  int idx = blockIdx.x * 256 + threadIdx.x;
  int c = idx & 127;
  int n = idx >> 7;
  int l = n >> 12;
  int s = n & 4095;
  xt[idx] = x[((l * 128 + c) << 12) + s];
}

__global__ __launch_bounds__(256) void k_transpose_out(const float* __restrict__ xt,
                                                       float* __restrict__ out) {
  int idx = blockIdx.x * 256 + threadIdx.x;
  int s = idx & 4095;
  int c = (idx >> 12) & 127;
  int l = idx >> 19;
  out[idx] = xt[(((l << 12) | s) << 7) + c];
}

// ---------------- layernorm fp32 in -> bf16 out, one wave per row ----------------
__global__ __launch_bounds__(256) void k_ln_f2b(const float* __restrict__ X,
                                                const float* __restrict__ g,
                                                const float* __restrict__ b,
                                                u16* __restrict__ Y, int M) {
  int n = blockIdx.x * 4 + (threadIdx.x >> 6);
  if (n >= M) return;
  int lane = threadIdx.x & 63;
  const float* row = X + (long)n * 128;
  float2 v = *(const float2*)(row + lane * 2);
  float s = v.x + v.y;
#pragma unroll
  for (int o = 32; o > 0; o >>= 1) s += __shfl_xor(s, o);
  float mu = s * (1.0f / 128.0f);
  float dx = v.x - mu, dy = v.y - mu;
  float q = dx * dx + dy * dy;
#pragma unroll
  for (int o = 32; o > 0; o >>= 1) q += __shfl_xor(q, o);
  float rs = rsqrtf(q * (1.0f / 128.0f) + 1e-5f);
  float2 gv = *(const float2*)(g + lane * 2);
  float2 bv = *(const float2*)(b + lane * 2);
  ushort2 o2;
  o2.x = f2bf(dx * rs * gv.x + bv.x);
  o2.y = f2bf(dy * rs * gv.y + bv.y);
  *(ushort2*)(Y + (long)n * 128 + lane * 2) = o2;
}

// ---------------- weight repack: W[oc][ic][tap] fp32 -> Wb[tap][oc][ic] bf16 ----------------
__global__ __launch_bounds__(256) void k_repack_bf(const float* __restrict__ W,
                                                   u16* __restrict__ Wb,
                                                   int lgOC, int lgIC, int NT, long tot) {
  long idx = (long)blockIdx.x * 256 + threadIdx.x;
  if (idx >= tot) return;
  int ic = (int)(idx & ((1 << lgIC) - 1));
  long r = idx >> lgIC;
  int oc = (int)(r & ((1 << lgOC) - 1));
  int t = (int)(r >> lgOC);
  Wb[idx] = f2bf(W[(((long)oc << lgIC) | ic) * NT + t]);
}

// ---------------- conv-as-gather-GEMM, bf16 MFMA ----------------
// mode 0: 3x1x1x1 along L, half-local padding. NT=3
// mode 1: 1x3x3x3 over (d,h,w), optional stride. NT=27
// mode 2: 3x3x3x3 over (l,d,h,w). NT=81
// flags: 1=ACC into fp32 Y, 2=RELU, 4=bf16 out (else fp32 out)
template <int MT>
__global__ __launch_bounds__(256) void k_conv_mfma(
    const u16* __restrict__ X, const u16* __restrict__ W3,
    const float* __restrict__ bias, void* __restrict__ Yv,
    int M, int IC, int OC, int mode, int NT,
    int lgWo, int lgHo, int lgDo,
    int lgWi, int lgHi, int lgDi,
    int Li, int Di, int Hi, int Wi,
    int sL, int sD, int sH, int sW, int flags) {
  __shared__ u16 As[MT * PITCH];
  __shared__ u16 Bs[64 * PITCH];
  constexpr int NA = MT / 64;
  int tid = threadIdx.x;
  int wave = tid >> 6, lane = tid & 63;
  int quad = lane >> 4, l15 = lane & 15;
  int m0 = blockIdx.x * MT;
  int oc0 = blockIdx.y * 64;

  // staging thread coords
  int srl = (MT == 128) ? (tid >> 1) : (tid >> 2);
  int sao = (MT == 128) ? ((tid & 1) * 8) : ((tid & 3) * 8);
  int sboc = tid >> 2, sbo = (tid & 3) * 8;

  // token decode (tap-invariant) for this thread's staging row
  int sm = m0 + srl;
  bool mv = sm < M;
  int w = sm & ((1 << lgWo) - 1);
  int h = (sm >> lgWo) & ((1 << lgHo) - 1);
  int d = (sm >> (lgWo + lgHo)) & ((1 << lgDo) - 1);
  int l = sm >> (lgWo + lgHo + lgDo);

  int c0 = 0, c1 = 0, c2 = 0, c3 = 0;  // base-3 tap counters (w,h,d,l fastest->slowest)
  auto comp_nb = [&]() -> long {
    if (!mv) return -1;
    int li, di, hi, wi; bool ok;
    if (mode == 0) {
      int dl = c0 - 1;
      int ll = (l & 1) + dl;
      ok = (ll >= 0 && ll < 2);
      li = l + dl; di = d; hi = h; wi = w;
    } else if (mode == 1) {
      li = l * sL; di = d * sD + c2 - 1; hi = h * sH + c1 - 1; wi = w * sW + c0 - 1;
      ok = ((unsigned)di < (unsigned)Di) && ((unsigned)hi < (unsigned)Hi) &&
           ((unsigned)wi < (unsigned)Wi);
    } else {
      li = l + c3 - 1; di = d + c2 - 1; hi = h + c1 - 1; wi = w + c0 - 1;
      ok = ((unsigned)li < (unsigned)Li) && ((unsigned)di < (unsigned)Di) &&
           ((unsigned)hi < (unsigned)Hi) && ((unsigned)wi < (unsigned)Wi);
    }
    if (!ok) return -1;
    return ((((long)((li << lgDi) + di) << lgHi) + hi) << lgWi) + wi;
  };

  long nb = comp_nb();
  const u16* wt = W3 + (long)(oc0 + sboc) * IC + sbo;
  long wstep = (long)OC * IC;
  int kmask = (IC >> 5) - 1;
  int total = NT * (IC >> 5);

  const bf16x8 Z = {0, 0, 0, 0, 0, 0, 0, 0};
  bf16x8 ra0 = Z, ra1 = Z, rb;
  if (nb >= 0) {
    const u16* p = X + nb * IC + sao;
    ra0 = *(const bf16x8*)p;
    if constexpr (MT == 128) ra1 = *(const bf16x8*)(p + 16);
  }
  rb = *(const bf16x8*)wt;

  f32x4 acc[NA][4];
#pragma unroll
  for (int i = 0; i < NA; ++i)
#pragma unroll
    for (int j = 0; j < 4; ++j) acc[i][j] = {0.f, 0.f, 0.f, 0.f};

  int wrow = wave * (MT / 4);  // 32 or 16

  for (int ks = 0; ks < total; ++ks) {
    __syncthreads();
    *(bf16x8*)&As[srl * PITCH + sao] = ra0;
    if constexpr (MT == 128) *(bf16x8*)&As[srl * PITCH + sao + 16] = ra1;
    *(bf16x8*)&Bs[sboc * PITCH + sbo] = rb;
    __syncthreads();
    int ksn = ks + 1;
    if (ksn < total) {
      int k0n = (ksn & kmask) << 5;
      if ((ksn & kmask) == 0) {
        wt += wstep;
        if (++c0 == 3) { c0 = 0; if (++c1 == 3) { c1 = 0; if (++c2 == 3) { c2 = 0; ++c3; } } }
        nb = comp_nb();
      }
      ra0 = Z; ra1 = Z;
      if (nb >= 0) {
        const u16* p = X + nb * IC + k0n + sao;
        ra0 = *(const bf16x8*)p;
        if constexpr (MT == 128) ra1 = *(const bf16x8*)(p + 16);
      }
      rb = *(const bf16x8*)(wt + k0n);
    }
    // MFMA on current LDS tile
    bf16x8 a0 = *(const bf16x8*)&As[(wrow + l15) * PITCH + quad * 8];
    bf16x8 a1;
    if constexpr (MT == 128) a1 = *(const bf16x8*)&As[(wrow + 16 + l15) * PITCH + quad * 8];
#pragma unroll
    for (int j = 0; j < 4; ++j) {
      bf16x8 b = *(const bf16x8*)&Bs[(j * 16 + l15) * PITCH + quad * 8];
      acc[0][j] = __builtin_amdgcn_mfma_f32_16x16x32_bf16(a0, b, acc[0][j], 0, 0, 0);
      if constexpr (MT == 128)
        acc[1][j] = __builtin_amdgcn_mfma_f32_16x16x32_bf16(a1, b, acc[1][j], 0, 0, 0);
    }
  }

  // epilogue: C/D layout col=lane&15, row=quad*4+reg
  int col = oc0 + l15;
#pragma unroll
  for (int j = 0; j < 4; ++j) {
    float bj = bias[col + j * 16];
#pragma unroll
    for (int i = 0; i < NA; ++i) {
      int rbase = m0 + wrow + i * 16 + quad * 4;
#pragma unroll
      for (int r = 0; r < 4; ++r) {
        int row = rbase + r;
        if (row >= M) continue;
        float v = acc[i][j][r] + bj;
        if (flags & 2) v = fmaxf(v, 0.f);
        long off = (long)row * OC + col + j * 16;
        if (flags & 4) {
          ((u16*)Yv)[off] = f2bf(v);
        } else if (flags & 1) {
          ((float*)Yv)[off] += v;
        } else {
          ((float*)Yv)[off] = v;
        }
      }
    }
  }
}

// ---------------- TLG windowed cross attention: 8q x 8k per (window, head), bf16 ----------------
__global__ __launch_bounds__(256) void k_tlg_attn(const u16* __restrict__ Q,
                                                  const u16* __restrict__ K,
                                                  const u16* __restrict__ V,
                                                  u16* __restrict__ Y) {
  int gw = blockIdx.x * 4 + (threadIdx.x >> 6);
  int lane = threadIdx.x & 63;
  int head = gw & 7;
  int win = gw >> 3;
  int wB = win & 7, hB = (win >> 3) & 7, dB = (win >> 6) & 7, l = win >> 9;
  int i = lane >> 3, j = lane & 7;
  int nq = (l << 12) | ((dB * 2 + (i >> 2)) << 8) | ((hB * 2 + ((i >> 1) & 1)) << 4) |
           (wB * 2 + (i & 1));
  int lk = l ^ 2;
  int nk = (lk << 12) | ((dB * 2 + (j >> 2)) << 8) | ((hB * 2 + ((j >> 1) & 1)) << 4) |
           (wB * 2 + (j & 1));
  int hoff = head * 16;
  const u16* qp = Q + (long)nq * 128 + hoff;
  const u16* kp = K + (long)nk * 128 + hoff;
  float s = 0.f;
#pragma unroll
  for (int t = 0; t < 16; t += 4) {
    float4 a = load4bf(qp + t);
    float4 b = load4bf(kp + t);
    s += a.x * b.x + a.y * b.y + a.z * b.z + a.w * b.w;
  }
  s *= 0.25f;
  float mx = s;
#pragma unroll
  for (int o = 1; o < 8; o <<= 1) mx = fmaxf(mx, __shfl_xor(mx, o));
  float e = __expf(s - mx);
  float sum = e;
#pragma unroll
  for (int o = 1; o < 8; o <<= 1) sum += __shfl_xor(sum, o);
  float p = e / sum;
  const u16* vp = V + (long)nk * 128 + hoff;
  float y[16];
#pragma unroll
  for (int t = 0; t < 16; t += 4) {
    float4 vv = load4bf(vp + t);
    y[t] = p * vv.x; y[t + 1] = p * vv.y; y[t + 2] = p * vv.z; y[t + 3] = p * vv.w;
  }
#pragma unroll
  for (int o = 1; o < 8; o <<= 1) {
#pragma unroll
    for (int t = 0; t < 16; ++t) y[t] += __shfl_xor(y[t], o);
  }
  if (j == 0) {
    u16* yp = Y + (long)nq * 128 + hoff;
    u16 tmp[16];
#pragma unroll
    for (int t = 0; t < 16; ++t) tmp[t] = f2bf(y[t]);
    *(uint4*)(yp) = *(uint4*)tmp;
    *(uint4*)(yp + 8) = *(uint4*)(tmp + 8);
  }
}

// ---------------- SLG global attention: one wave per (query, head); NK keys, bf16 ----------------
__global__ __launch_bounds__(256) void k_slg_attn(const u16* __restrict__ Q,
                                                  const u16* __restrict__ K,
                                                  const u16* __restrict__ V,
                                                  u16* __restrict__ Y, int NK) {
  int gw = blockIdx.x * 4 + (threadIdx.x >> 6);
  int lane = threadIdx.x & 63;
  int head = gw & 7;
  int nq = gw >> 3;
  int hoff = head * 16;
  const u16* qp = Q + (long)nq * 128 + hoff;
  float qv[16];
#pragma unroll
  for (int t = 0; t < 16; t += 4) {
    float4 a = load4bf(qp + t);
    qv[t] = a.x; qv[t + 1] = a.y; qv[t + 2] = a.z; qv[t + 3] = a.w;
  }
  float sc[17];
  float smax = -1e30f;
#pragma unroll
  for (int cc = 0; cc < 17; ++cc) {
    int k = lane + cc * 64;
    float s = -1e30f;
    if (k < NK) {
      const u16* kp = K + (long)k * 128 + hoff;
      float s0 = 0.f;
#pragma unroll
      for (int t = 0; t < 16; t += 4) {
        float4 b = load4bf(kp + t);
        s0 += qv[t] * b.x + qv[t + 1] * b.y + qv[t + 2] * b.z + qv[t + 3] * b.w;
      }
      s = s0 * 0.25f;
    }
    sc[cc] = s;
    smax = fmaxf(smax, s);
  }
#pragma unroll
  for (int o = 32; o > 0; o >>= 1) smax = fmaxf(smax, __shfl_xor(smax, o));
  float y[16] = {0.f};
  float sum = 0.f;
#pragma unroll
  for (int cc = 0; cc < 17; ++cc) {
    int k = lane + cc * 64;
    if (k < NK) {
      float p = __expf(sc[cc] - smax);
      sum += p;
      const u16* vp = V + (long)k * 128 + hoff;
#pragma unroll
      for (int t = 0; t < 16; t += 4) {
        float4 vv = load4bf(vp + t);
        y[t] += p * vv.x; y[t + 1] += p * vv.y; y[t + 2] += p * vv.z; y[t + 3] += p * vv.w;
      }
    }
  }
#pragma unroll
  for (int o = 32; o > 0; o >>= 1) sum += __shfl_xor(sum, o);
#pragma unroll
  for (int o = 32; o > 0; o >>= 1) {
#pragma unroll
    for (int t = 0; t < 16; ++t) y[t] += __shfl_xor(y[t], o);
  }
  if (lane == 0) {
    float inv = 1.0f / sum;
    u16* yp = Y + (long)nq * 128 + hoff;
    u16 tmp[16];
#pragma unroll
    for (int t = 0; t < 16; ++t) tmp[t] = f2bf(y[t] * inv);
    *(uint4*)(yp) = *(uint4*)tmp;
    *(uint4*)(yp + 8) = *(uint4*)(tmp + 8);
  }
}

static inline int ilg(int v) { int r = 0; while ((1 << r) < v) ++r; return r; }

extern "C" void kernel_launch(void* const* d_in, const int* in_sizes, int n_in,
                              void* d_out, int out_size, void* d_ws, size_t ws_size,
                              hipStream_t stream) {
  (void)in_sizes; (void)n_in; (void)out_size; (void)ws_size;
  const float* x    = (const float*)d_in[0];
  const float* n1_w = (const float*)d_in[1];  const float* n1_b = (const float*)d_in[2];
  const float* n2_w = (const float*)d_in[3];  const float* n2_b = (const float*)d_in[4];
  const float* n3_w = (const float*)d_in[5];  const float* n3_b = (const float*)d_in[6];
  const float* sn_w = (const float*)d_in[7];  const float* sn_b = (const float*)d_in[8];
  const float* tq_w = (const float*)d_in[9];  const float* tq_b = (const float*)d_in[10];
  const float* tk_w = (const float*)d_in[11]; const float* tk_b = (const float*)d_in[12];
  const float* tv_w = (const float*)d_in[13]; const float* tv_b = (const float*)d_in[14];
  const float* tp_w = (const float*)d_in[15]; const float* tp_b = (const float*)d_in[16];
  const float* sq_w = (const float*)d_in[17]; const float* sq_b = (const float*)d_in[18];
  const float* sk_w = (const float*)d_in[19]; const float* sk_b = (const float*)d_in[20];
  const float* sv_w = (const float*)d_in[21]; const float* sv_b = (const float*)d_in[22];
  const float* sp_w = (const float*)d_in[23]; const float* sp_b = (const float*)d_in[24];
  const float* sf_w = (const float*)d_in[25]; const float* sf_b = (const float*)d_in[26];
  const float* sc_w = (const float*)d_in[27]; const float* sc_b = (const float*)d_in[28];
  const float* m1_w = (const float*)d_in[29]; const float* m1_b = (const float*)d_in[30];
  const float* m2_w = (const float*)d_in[31]; const float* m2_b = (const float*)d_in[32];

  char* p = (char*)d_ws;
  auto alloc = [&](size_t bytes) { char* r = p; p += (bytes + 255) & ~(size_t)255; return r; };
  const long N = 16384;
  float* X0 = (float*)alloc(N * 128 * 4);
  u16* XN = (u16*)alloc(N * 128 * 2);
  u16* Qb = (u16*)alloc(N * 128 * 2);
  u16* Kb = (u16*)alloc(N * 128 * 2);
  u16* Vb = (u16*)alloc(N * 128 * 2);
  u16* Yb = (u16*)alloc(N * 128 * 2);
  u16* H  = (u16*)alloc(N * 512 * 2);
  u16* XC = (u16*)alloc(8 * 128 * 2);
  u16* XF = (u16*)alloc(1024 * 128 * 2);
  float* Kf = (float*)alloc(1032 * 128 * 4);
  float* Vf = (float*)alloc(1032 * 128 * 4);
  u16* tq2 = (u16*)alloc(49152 * 2);  u16* tk2 = (u16*)alloc(49152 * 2);
  u16* tv2 = (u16*)alloc(49152 * 2);  u16* tp2 = (u16*)alloc(49152 * 2);
  u16* sq2 = (u16*)alloc(442368 * 2); u16* sk2 = (u16*)alloc(442368 * 2);
  u16* sv2 = (u16*)alloc(442368 * 2); u16* sp2 = (u16*)alloc(442368 * 2);
  u16* sf2 = (u16*)alloc(442368 * 2); u16* sc2 = (u16*)alloc(442368 * 2);
  u16* m12 = (u16*)alloc(5308416L * 2);
  u16* m22 = (u16*)alloc(5308416L * 2);

  auto rp = [&](const float* W, u16* Wb, int OC, int IC, int NT) {
    long tot = (long)OC * IC * NT;
    k_repack_bf<<<(int)((tot + 255) / 256), 256, 0, stream>>>(W, Wb, ilg(OC), ilg(IC), NT, tot);
  };
  rp(tq_w, tq2, 128, 128, 3);  rp(tk_w, tk2, 128, 128, 3);
  rp(tv_w, tv2, 128, 128, 3);  rp(tp_w, tp2, 128, 128, 3);
  rp(sq_w, sq2, 128, 128, 27); rp(sk_w, sk2, 128, 128, 27);
  rp(sv_w, sv2, 128, 128, 27); rp(sp_w, sp2, 128, 128, 27);
  rp(sf_w, sf2, 128, 128, 27); rp(sc_w, sc2, 128, 128, 27);
  rp(m1_w, m12, 512, 128, 81); rp(m2_w, m22, 128, 512, 81);

  auto conv = [&](const u16* Xp, const u16* Wp, const float* Bp, void* Yp,
                  int M, int IC, int OC, int mode, int NT,
                  int Do, int Ho, int Wo, int Li, int Di, int Hi, int Wi,
                  int sL, int sD, int sH, int sW, int flags) {
    bool big = ((long)(M / 128) * (OC / 64) >= 400) && (M % 128 == 0);
    int lgWo = ilg(Wo), lgHo = ilg(Ho), lgDo = ilg(Do);
    int lgWi = ilg(Wi), lgHi = ilg(Hi), lgDi = ilg(Di);
    if (big) {
      dim3 g(M / 128, OC / 64);
      k_conv_mfma<128><<<g, 256, 0, stream>>>(Xp, Wp, Bp, Yp, M, IC, OC, mode, NT,
                                              lgWo, lgHo, lgDo, lgWi, lgHi, lgDi,
                                              Li, Di, Hi, Wi, sL, sD, sH, sW, flags);
    } else {
      dim3 g((M + 63) / 64, OC / 64);
      k_conv_mfma<64><<<g, 256, 0, stream>>>(Xp, Wp, Bp, Yp, M, IC, OC, mode, NT,
                                             lgWo, lgHo, lgDo, lgWi, lgHi, lgDi,
                                             Li, Di, Hi, Wi, sL, sD, sH, sW, flags);
    }
  };

  k_transpose_in<<<8192, 256, 0, stream>>>(x, X0);

  // ---- TLG branch ----
  k_ln_f2b<<<4096, 256, 0, stream>>>(X0, n1_w, n1_b, XN, 16384);
  conv(XN, tq2, tq_b, Qb, 16384, 128, 128, 0, 3, 16, 16, 16, 4, 16, 16, 16, 1, 1, 1, 1, 4);
  conv(XN, tk2, tk_b, Kb, 16384, 128, 128, 0, 3, 16, 16, 16, 4, 16, 16, 16, 1, 1, 1, 1, 4);
  conv(XN, tv2, tv_b, Vb, 16384, 128, 128, 0, 3, 16, 16, 16, 4, 16, 16, 16, 1, 1, 1, 1, 4);
  k_tlg_attn<<<4096, 256, 0, stream>>>(Qb, Kb, Vb, Yb);
  conv(Yb, tp2, tp_b, X0, 16384, 128, 128, 0, 3, 16, 16, 16, 4, 16, 16, 16, 1, 1, 1, 1, 1);

  // ---- SLG branch ----
  k_ln_f2b<<<4096, 256, 0, stream>>>(X0, n2_w, n2_b, XN, 16384);
  conv(XN, sq2, sq_b, Qb, 16384, 128, 128, 1, 27, 16, 16, 16, 4, 16, 16, 16, 1, 1, 1, 1, 4);
  conv(XN, sc2, sc_b, XC, 8,    128, 128, 1, 27, 2, 2, 2,   4, 16, 16, 16, 4, 8, 8, 8, 4);
  conv(XN, sf2, sf_b, XF, 1024, 128, 128, 1, 27, 8, 8, 8,   4, 16, 16, 16, 2, 2, 2, 2, 4);
  conv(XC, sk2, sk_b, Kf,            8,    128, 128, 1, 27, 2, 2, 2, 1, 2, 2, 2, 1, 1, 1, 1, 0);
  conv(XF, sk2, sk_b, Kf + 8 * 128,  1024, 128, 128, 1, 27, 8, 8, 8, 2, 8, 8, 8, 1, 1, 1, 1, 0);
  conv(XC, sv2, sv_b, Vf,            8,    128, 128, 1, 27, 2, 2, 2, 1, 2, 2, 2, 1, 1, 1, 1, 0);
  conv(XF, sv2, sv_b, Vf + 8 * 128,  1024, 128, 128, 1, 27, 8, 8, 8, 2, 8, 8, 8, 1, 1, 1, 1, 0);
  k_ln_f2b<<<258, 256, 0, stream>>>(Kf, sn_w, sn_b, Kb, 1032);
  k_ln_f2b<<<258, 256, 0, stream>>>(Vf, sn_w, sn_b, Vb, 1032);
  k_slg_attn<<<32768, 256, 0, stream>>>(Qb, Kb, Vb, Yb, 1032);
  conv(Yb, sp2, sp_b, X0, 16384, 128, 128, 1, 27, 16, 16, 16, 4, 16, 16, 16, 1, 1, 1, 1, 1);

  // ---- MLP branch ----
  k_ln_f2b<<<4096, 256, 0, stream>>>(X0, n3_w, n3_b, XN, 16384);
  conv(XN, m12, m1_b, H, 16384, 128, 512, 2, 81, 16, 16, 16, 4, 16, 16, 16, 1, 1, 1, 1, 6);
  conv(H, m22, m2_b, X0, 16384, 512, 128, 2, 81, 16, 16, 16, 4, 16, 16, 16, 1, 1, 1, 1, 1);

  k_transpose_out<<<8192, 256, 0, stream>>>(X0, (float*)d_out);
}

// Round 3
// 1668.905 us; speedup vs baseline: 5.5401x; 1.5150x over previous
//
#include <hip/hip_runtime.h>

typedef unsigned short u16;
typedef __attribute__((ext_vector_type(8))) short bf16x8;
typedef __attribute__((ext_vector_type(4))) float f32x4;

#define PITCH 40  // shorts per LDS row (80B): 8 rows cover all 32 banks, 2-way free

__device__ __forceinline__ u16 f2bf(float f) {
  union { float f; unsigned u; } v; v.f = f;
  unsigned r = v.u + 0x7fffu + ((v.u >> 16) & 1u);
  return (u16)(r >> 16);
}
__device__ __forceinline__ float bf2f(u16 h) {
  union { unsigned u; float f; } v; v.u = ((unsigned)h) << 16;
  return v.f;
}
__device__ __forceinline__ float4 load4bf(const u16* p) {
  ushort4 h = *(const ushort4*)p;
  return make_float4(bf2f(h.x), bf2f(h.y), bf2f(h.z), bf2f(h.w));
}

// ---------------- transpose (l,c,d,h,w) -> token-major [n=(l,d,h,w), c] fp32 ----------------
__global__ __launch_bounds__(256) void k_transpose_in(const float* __restrict__ x,
                                                      float* __restrict__ xt) {
  int idx = blockIdx.x * 256 + threadIdx.x;
  int c = idx & 127;
  int n = idx >> 7;
  int l = n >> 12;
  int s = n & 4095;
  xt[idx] = x[((l * 128 + c) << 12) + s];
}

__global__ __launch_bounds__(256) void k_transpose_out(const float* __restrict__ xt,
                                                       float* __restrict__ out) {
  int idx = blockIdx.x * 256 + threadIdx.x;
  int s = idx & 4095;
  int c = (idx >> 12) & 127;
  int l = idx >> 19;
  out[idx] = xt[(((l << 12) | s) << 7) + c];
}

// ---------------- layernorm fp32 in -> bf16 out, one wave per row ----------------
__global__ __launch_bounds__(256) void k_ln_f2b(const float* __restrict__ X,
                                                const float* __restrict__ g,
                                                const float* __restrict__ b,
                                                u16* __restrict__ Y, int M) {
  int n = blockIdx.x * 4 + (threadIdx.x >> 6);
  if (n >= M) return;
  int lane = threadIdx.x & 63;
  const float* row = X + (long)n * 128;
  float2 v = *(const float2*)(row + lane * 2);
  float s = v.x + v.y;
#pragma unroll
  for (int o = 32; o > 0; o >>= 1) s += __shfl_xor(s, o);
  float mu = s * (1.0f / 128.0f);
  float dx = v.x - mu, dy = v.y - mu;
  float q = dx * dx + dy * dy;
#pragma unroll
  for (int o = 32; o > 0; o >>= 1) q += __shfl_xor(q, o);
  float rs = rsqrtf(q * (1.0f / 128.0f) + 1e-5f);
  float2 gv = *(const float2*)(g + lane * 2);
  float2 bv = *(const float2*)(b + lane * 2);
  ushort2 o2;
  o2.x = f2bf(dx * rs * gv.x + bv.x);
  o2.y = f2bf(dy * rs * gv.y + bv.y);
  *(ushort2*)(Y + (long)n * 128 + lane * 2) = o2;
}

// ---------------- weight repack: W[oc][ic][tap] fp32 -> Wb[tap][oc][ic] bf16 ----------------
__global__ __launch_bounds__(256) void k_repack_bf(const float* __restrict__ W,
                                                   u16* __restrict__ Wb,
                                                   int lgOC, int lgIC, int NT, long tot) {
  long idx = (long)blockIdx.x * 256 + threadIdx.x;
  if (idx >= tot) return;
  int ic = (int)(idx & ((1 << lgIC) - 1));
  long r = idx >> lgIC;
  int oc = (int)(r & ((1 << lgOC) - 1));
  int t = (int)(r >> lgOC);
  Wb[idx] = f2bf(W[(((long)oc << lgIC) | ic) * NT + t]);
}

// ---------------- conv-as-gather-GEMM, bf16 MFMA ----------------
// mode 0: 3x1x1x1 along L, half-local padding. NT=3
// mode 1: 1x3x3x3 over (d,h,w), optional stride. NT=27
// mode 2: 3x3x3x3 over (l,d,h,w). NT=81
// flags: 1=ACC into fp32 Y, 2=RELU, 4=bf16 out (else fp32 out)
template <int MT>
__global__ __launch_bounds__(256) void k_conv_mfma(
    const u16* __restrict__ X, const u16* __restrict__ W3,
    const float* __restrict__ bias, void* __restrict__ Yv,
    int M, int IC, int OC, int mode, int NT,
    int lgWo, int lgHo, int lgDo,
    int lgWi, int lgHi, int lgDi,
    int Li, int Di, int Hi, int Wi,
    int sL, int sD, int sH, int sW, int flags) {
  __shared__ u16 As[MT * PITCH];
  __shared__ u16 Bs[64 * PITCH];
  constexpr int NA = MT / 64;
  int tid = threadIdx.x;
  int wave = tid >> 6, lane = tid & 63;
  int quad = lane >> 4, l15 = lane & 15;
  int m0 = blockIdx.x * MT;
  int oc0 = blockIdx.y * 64;

  int srl = (MT == 128) ? (tid >> 1) : (tid >> 2);
  int sao = (MT == 128) ? ((tid & 1) * 8) : ((tid & 3) * 8);
  int sboc = tid >> 2, sbo = (tid & 3) * 8;

  int sm = m0 + srl;
  bool mv = sm < M;
  int w = sm & ((1 << lgWo) - 1);
  int h = (sm >> lgWo) & ((1 << lgHo) - 1);
  int d = (sm >> (lgWo + lgHo)) & ((1 << lgDo) - 1);
  int l = sm >> (lgWo + lgHo + lgDo);

  int c0 = 0, c1 = 0, c2 = 0, c3 = 0;
  auto comp_nb = [&]() -> long {
    if (!mv) return -1;
    int li, di, hi, wi; bool ok;
    if (mode == 0) {
      int dl = c0 - 1;
      int ll = (l & 1) + dl;
      ok = (ll >= 0 && ll < 2);
      li = l + dl; di = d; hi = h; wi = w;
    } else if (mode == 1) {
      li = l * sL; di = d * sD + c2 - 1; hi = h * sH + c1 - 1; wi = w * sW + c0 - 1;
      ok = ((unsigned)di < (unsigned)Di) && ((unsigned)hi < (unsigned)Hi) &&
           ((unsigned)wi < (unsigned)Wi);
    } else {
      li = l + c3 - 1; di = d + c2 - 1; hi = h + c1 - 1; wi = w + c0 - 1;
      ok = ((unsigned)li < (unsigned)Li) && ((unsigned)di < (unsigned)Di) &&
           ((unsigned)hi < (unsigned)Hi) && ((unsigned)wi < (unsigned)Wi);
    }
    if (!ok) return -1;
    return ((((long)((li << lgDi) + di) << lgHi) + hi) << lgWi) + wi;
  };

  long nb = comp_nb();
  const u16* wt = W3 + (long)(oc0 + sboc) * IC + sbo;
  long wstep = (long)OC * IC;
  int kmask = (IC >> 5) - 1;
  int total = NT * (IC >> 5);

  const bf16x8 Z = {0, 0, 0, 0, 0, 0, 0, 0};
  bf16x8 ra0 = Z, ra1 = Z, rb;
  if (nb >= 0) {
    const u16* p = X + nb * IC + sao;
    ra0 = *(const bf16x8*)p;
    if constexpr (MT == 128) ra1 = *(const bf16x8*)(p + 16);
  }
  rb = *(const bf16x8*)wt;

  f32x4 acc[NA][4];
#pragma unroll
  for (int i = 0; i < NA; ++i)
#pragma unroll
    for (int j = 0; j < 4; ++j) acc[i][j] = {0.f, 0.f, 0.f, 0.f};

  int wrow = wave * (MT / 4);

  for (int ks = 0; ks < total; ++ks) {
    __syncthreads();
    *(bf16x8*)&As[srl * PITCH + sao] = ra0;
    if constexpr (MT == 128) *(bf16x8*)&As[srl * PITCH + sao + 16] = ra1;
    *(bf16x8*)&Bs[sboc * PITCH + sbo] = rb;
    __syncthreads();
    int ksn = ks + 1;
    if (ksn < total) {
      int k0n = (ksn & kmask) << 5;
      if ((ksn & kmask) == 0) {
        wt += wstep;
        if (++c0 == 3) { c0 = 0; if (++c1 == 3) { c1 = 0; if (++c2 == 3) { c2 = 0; ++c3; } } }
        nb = comp_nb();
      }
      ra0 = Z; ra1 = Z;
      if (nb >= 0) {
        const u16* p = X + nb * IC + k0n + sao;
        ra0 = *(const bf16x8*)p;
        if constexpr (MT == 128) ra1 = *(const bf16x8*)(p + 16);
      }
      rb = *(const bf16x8*)(wt + k0n);
    }
    bf16x8 a0 = *(const bf16x8*)&As[(wrow + l15) * PITCH + quad * 8];
    bf16x8 a1;
    if constexpr (MT == 128) a1 = *(const bf16x8*)&As[(wrow + 16 + l15) * PITCH + quad * 8];
#pragma unroll
    for (int j = 0; j < 4; ++j) {
      bf16x8 b = *(const bf16x8*)&Bs[(j * 16 + l15) * PITCH + quad * 8];
      acc[0][j] = __builtin_amdgcn_mfma_f32_16x16x32_bf16(a0, b, acc[0][j], 0, 0, 0);
      if constexpr (MT == 128)
        acc[1][j] = __builtin_amdgcn_mfma_f32_16x16x32_bf16(a1, b, acc[1][j], 0, 0, 0);
    }
  }

  int col = oc0 + l15;
#pragma unroll
  for (int j = 0; j < 4; ++j) {
    float bj = bias[col + j * 16];
#pragma unroll
    for (int i = 0; i < NA; ++i) {
      int rbase = m0 + wrow + i * 16 + quad * 4;
#pragma unroll
      for (int r = 0; r < 4; ++r) {
        int row = rbase + r;
        if (row >= M) continue;
        float v = acc[i][j][r] + bj;
        if (flags & 2) v = fmaxf(v, 0.f);
        long off = (long)row * OC + col + j * 16;
        if (flags & 4) {
          ((u16*)Yv)[off] = f2bf(v);
        } else if (flags & 1) {
          ((float*)Yv)[off] += v;
        } else {
          ((float*)Yv)[off] = v;
        }
      }
    }
  }
}

// ---------------- TLG windowed cross attention: 8q x 8k per (window, head), bf16 ----------------
__global__ __launch_bounds__(256) void k_tlg_attn(const u16* __restrict__ Q,
                                                  const u16* __restrict__ K,
                                                  const u16* __restrict__ V,
                                                  u16* __restrict__ Y) {
  int gw = blockIdx.x * 4 + (threadIdx.x >> 6);
  int lane = threadIdx.x & 63;
  int head = gw & 7;
  int win = gw >> 3;
  int wB = win & 7, hB = (win >> 3) & 7, dB = (win >> 6) & 7, l = win >> 9;
  int i = lane >> 3, j = lane & 7;
  int nq = (l << 12) | ((dB * 2 + (i >> 2)) << 8) | ((hB * 2 + ((i >> 1) & 1)) << 4) |
           (wB * 2 + (i & 1));
  int lk = l ^ 2;
  int nk = (lk << 12) | ((dB * 2 + (j >> 2)) << 8) | ((hB * 2 + ((j >> 1) & 1)) << 4) |
           (wB * 2 + (j & 1));
  int hoff = head * 16;
  const u16* qp = Q + (long)nq * 128 + hoff;
  const u16* kp = K + (long)nk * 128 + hoff;
  float s = 0.f;
#pragma unroll
  for (int t = 0; t < 16; t += 4) {
    float4 a = load4bf(qp + t);
    float4 b = load4bf(kp + t);
    s += a.x * b.x + a.y * b.y + a.z * b.z + a.w * b.w;
  }
  s *= 0.25f;
  float mx = s;
#pragma unroll
  for (int o = 1; o < 8; o <<= 1) mx = fmaxf(mx, __shfl_xor(mx, o));
  float e = __expf(s - mx);
  float sum = e;
#pragma unroll
  for (int o = 1; o < 8; o <<= 1) sum += __shfl_xor(sum, o);
  float p = e / sum;
  const u16* vp = V + (long)nk * 128 + hoff;
  float y[16];
#pragma unroll
  for (int t = 0; t < 16; t += 4) {
    float4 vv = load4bf(vp + t);
    y[t] = p * vv.x; y[t + 1] = p * vv.y; y[t + 2] = p * vv.z; y[t + 3] = p * vv.w;
  }
#pragma unroll
  for (int o = 1; o < 8; o <<= 1) {
#pragma unroll
    for (int t = 0; t < 16; ++t) y[t] += __shfl_xor(y[t], o);
  }
  if (j == 0) {
    u16* yp = Y + (long)nq * 128 + hoff;
    u16 tmp[16];
#pragma unroll
    for (int t = 0; t < 16; ++t) tmp[t] = f2bf(y[t]);
    *(uint4*)(yp) = *(uint4*)tmp;
    *(uint4*)(yp + 8) = *(uint4*)(tmp + 8);
  }
}

// ---------------- SLG K/V repack for flash attn ----------------
// Kh[h][k][d] = Kin[k][h*16+d]     (8*1032*16)
__global__ __launch_bounds__(256) void k_pack_kh(const u16* __restrict__ Kin,
                                                 u16* __restrict__ Kh) {
  int idx = blockIdx.x * 256 + threadIdx.x;
  if (idx >= 8 * 1032 * 16) return;
  int d = idx & 15;
  int r = idx >> 4;
  int k = r % 1032, h = r / 1032;
  Kh[idx] = Kin[k * 128 + h * 16 + d];
}
// Vt[h][d][k] = Vin[k][h*16+d]     (8*16*1032)
__global__ __launch_bounds__(256) void k_pack_vt(const u16* __restrict__ Vin,
                                                 u16* __restrict__ Vt) {
  int idx = blockIdx.x * 256 + threadIdx.x;
  if (idx >= 8 * 16 * 1032) return;
  int k = idx % 1032;
  int r = idx / 1032;
  int d = r & 15, h = r >> 4;
  Vt[idx] = Vin[k * 128 + h * 16 + d];
}

// ---------------- SLG MFMA flash attention ----------------
// Block: 1 head x 64 queries (4 waves x 16 q). K/V tiles of 64 keys in LDS.
// Q [16384][128] bf16, Kh [8][1032][16], Vt [8][16][1032], Y [16384][128] bf16.
__global__ __launch_bounds__(256) void k_slg_flash(const u16* __restrict__ Q,
                                                   const u16* __restrict__ Kh,
                                                   const u16* __restrict__ Vt,
                                                   u16* __restrict__ Y) {
  constexpr int NK = 1032;
  constexpr int NTILE = 17;  // ceil(1032/64)
  __shared__ __align__(16) u16 Ks[64 * 24];     // [key][dim], pitch 24 shorts
  __shared__ __align__(16) u16 Vs[16 * 72];     // [dim][key], pitch 72 shorts
  __shared__ __align__(16) u16 Ps[4][16 * 72];  // per wave: [q][key], pitch 72
  int tid = threadIdx.x;
  int wave = tid >> 6, lane = tid & 63;
  int quad = lane >> 4, l15 = lane & 15;
  int h = blockIdx.x & 7;
  int q0 = (blockIdx.x >> 3) * 64 + wave * 16;

  const bf16x8 Zb = {0, 0, 0, 0, 0, 0, 0, 0};
  // Q A-frag: m=l15 (query), k=quad*8+j (dim, zero-padded 16->32)
  bf16x8 qf = Zb;
  if (quad < 2) qf = *(const bf16x8*)(Q + (long)(q0 + l15) * 128 + h * 16 + quad * 8);

  const u16* Kbase = Kh + (long)h * NK * 16;
  const u16* Vbase = Vt + (long)h * 16 * NK;

  float mrow[4], lrow[4];
  f32x4 oacc = {0.f, 0.f, 0.f, 0.f};
#pragma unroll
  for (int r = 0; r < 4; ++r) { mrow[r] = -1e30f; lrow[r] = 0.f; }

  // staging coords
  int skey = tid >> 2, sch = (tid & 3) * 4;        // K: key, dim-chunk
  int svd = tid >> 4, svc = (tid & 15) * 4;        // V: dim row, key-chunk

  for (int t = 0; t < NTILE; ++t) {
    int k0 = t * 64;
    __syncthreads();
    {  // stage K tile [64][16] -> Ks pitch 24
      short4 v = {0, 0, 0, 0};
      int key = k0 + skey;
      if (key < NK) v = *(const short4*)(Kbase + key * 16 + sch);
      *(short4*)&Ks[skey * 24 + sch] = v;
    }
    {  // stage V^T tile [16][64] -> Vs pitch 72
      short4 v = {0, 0, 0, 0};
      int colb = k0 + svc;
      if (colb < NK) v = *(const short4*)(Vbase + svd * NK + colb);
      *(short4*)&Vs[svd * 72 + svc] = v;
    }
    __syncthreads();

    // QK^T: 4 n-subtiles of 16 keys
    f32x4 s[4];
#pragma unroll
    for (int sub = 0; sub < 4; ++sub) {
      bf16x8 b = Zb;  // B-frag: n=l15 (key), k=quad*8+j (dim)
      if (quad < 2) b = *(const bf16x8*)&Ks[(sub * 16 + l15) * 24 + quad * 8];
      f32x4 zero = {0.f, 0.f, 0.f, 0.f};
      s[sub] = __builtin_amdgcn_mfma_f32_16x16x32_bf16(qf, b, zero, 0, 0, 0);
    }
    // mask + scale; tile row max
    float pv[4][4];
    float tmax[4] = {-1e30f, -1e30f, -1e30f, -1e30f};
#pragma unroll
    for (int sub = 0; sub < 4; ++sub) {
      int key = k0 + sub * 16 + l15;
      bool valid = key < NK;
#pragma unroll
      for (int r = 0; r < 4; ++r) {
        float sv = valid ? s[sub][r] * 0.25f : -1e30f;
        pv[sub][r] = sv;
        tmax[r] = fmaxf(tmax[r], sv);
      }
    }
#pragma unroll
    for (int o = 1; o < 16; o <<= 1)
#pragma unroll
      for (int r = 0; r < 4; ++r) tmax[r] = fmaxf(tmax[r], __shfl_xor(tmax[r], o));

    float al[4], tsum[4] = {0.f, 0.f, 0.f, 0.f};
#pragma unroll
    for (int r = 0; r < 4; ++r) {
      float mn = fmaxf(mrow[r], tmax[r]);
      al[r] = __expf(mrow[r] - mn);
      mrow[r] = mn;
    }
#pragma unroll
    for (int sub = 0; sub < 4; ++sub)
#pragma unroll
      for (int r = 0; r < 4; ++r) {
        float pe = __expf(pv[sub][r] - mrow[r]);
        tsum[r] += pe;
        Ps[wave][(quad * 4 + r) * 72 + sub * 16 + l15] = f2bf(pe);
      }
#pragma unroll
    for (int o = 1; o < 16; o <<= 1)
#pragma unroll
      for (int r = 0; r < 4; ++r) tsum[r] += __shfl_xor(tsum[r], o);
#pragma unroll
    for (int r = 0; r < 4; ++r) {
      lrow[r] = lrow[r] * al[r] + tsum[r];
      oacc[r] *= al[r];
    }
    // PV: A=P (m=l15 query, k=key), B=V^T (n=l15 dim, k=key); K=64 as 2x K=32
    bf16x8 pa0 = *(const bf16x8*)&Ps[wave][l15 * 72 + quad * 8];
    bf16x8 pa1 = *(const bf16x8*)&Ps[wave][l15 * 72 + 32 + quad * 8];
    bf16x8 vb0 = *(const bf16x8*)&Vs[l15 * 72 + quad * 8];
    bf16x8 vb1 = *(const bf16x8*)&Vs[l15 * 72 + 32 + quad * 8];
    oacc = __builtin_amdgcn_mfma_f32_16x16x32_bf16(pa0, vb0, oacc, 0, 0, 0);
    oacc = __builtin_amdgcn_mfma_f32_16x16x32_bf16(pa1, vb1, oacc, 0, 0, 0);
  }

  // out: row=q0+quad*4+r, dim=l15
#pragma unroll
  for (int r = 0; r < 4; ++r) {
    float inv = 1.0f / lrow[r];
    Y[(long)(q0 + quad * 4 + r) * 128 + h * 16 + l15] = f2bf(oacc[r] * inv);
  }
}

static inline int ilg(int v) { int r = 0; while ((1 << r) < v) ++r; return r; }

extern "C" void kernel_launch(void* const* d_in, const int* in_sizes, int n_in,
                              void* d_out, int out_size, void* d_ws, size_t ws_size,
                              hipStream_t stream) {
  (void)in_sizes; (void)n_in; (void)out_size; (void)ws_size;
  const float* x    = (const float*)d_in[0];
  const float* n1_w = (const float*)d_in[1];  const float* n1_b = (const float*)d_in[2];
  const float* n2_w = (const float*)d_in[3];  const float* n2_b = (const float*)d_in[4];
  const float* n3_w = (const float*)d_in[5];  const float* n3_b = (const float*)d_in[6];
  const float* sn_w = (const float*)d_in[7];  const float* sn_b = (const float*)d_in[8];
  const float* tq_w = (const float*)d_in[9];  const float* tq_b = (const float*)d_in[10];
  const float* tk_w = (const float*)d_in[11]; const float* tk_b = (const float*)d_in[12];
  const float* tv_w = (const float*)d_in[13]; const float* tv_b = (const float*)d_in[14];
  const float* tp_w = (const float*)d_in[15]; const float* tp_b = (const float*)d_in[16];
  const float* sq_w = (const float*)d_in[17]; const float* sq_b = (const float*)d_in[18];
  const float* sk_w = (const float*)d_in[19]; const float* sk_b = (const float*)d_in[20];
  const float* sv_w = (const float*)d_in[21]; const float* sv_b = (const float*)d_in[22];
  const float* sp_w = (const float*)d_in[23]; const float* sp_b = (const float*)d_in[24];
  const float* sf_w = (const float*)d_in[25]; const float* sf_b = (const float*)d_in[26];
  const float* sc_w = (const float*)d_in[27]; const float* sc_b = (const float*)d_in[28];
  const float* m1_w = (const float*)d_in[29]; const float* m1_b = (const float*)d_in[30];
  const float* m2_w = (const float*)d_in[31]; const float* m2_b = (const float*)d_in[32];

  char* p = (char*)d_ws;
  auto alloc = [&](size_t bytes) { char* r = p; p += (bytes + 255) & ~(size_t)255; return r; };
  const long N = 16384;
  float* X0 = (float*)alloc(N * 128 * 4);
  u16* XN = (u16*)alloc(N * 128 * 2);
  u16* Qb = (u16*)alloc(N * 128 * 2);
  u16* Kb = (u16*)alloc(N * 128 * 2);
  u16* Vb = (u16*)alloc(N * 128 * 2);
  u16* Yb = (u16*)alloc(N * 128 * 2);
  u16* H  = (u16*)alloc(N * 512 * 2);
  u16* XC = (u16*)alloc(8 * 128 * 2);
  u16* XF = (u16*)alloc(1024 * 128 * 2);
  float* Kf = (float*)alloc(1032 * 128 * 4);
  float* Vf = (float*)alloc(1032 * 128 * 4);
  u16* Kh = (u16*)alloc(8 * 1032 * 16 * 2);
  u16* Vt = (u16*)alloc(8 * 16 * 1032 * 2);
  u16* tq2 = (u16*)alloc(49152 * 2);  u16* tk2 = (u16*)alloc(49152 * 2);
  u16* tv2 = (u16*)alloc(49152 * 2);  u16* tp2 = (u16*)alloc(49152 * 2);
  u16* sq2 = (u16*)alloc(442368 * 2); u16* sk2 = (u16*)alloc(442368 * 2);
  u16* sv2 = (u16*)alloc(442368 * 2); u16* sp2 = (u16*)alloc(442368 * 2);
  u16* sf2 = (u16*)alloc(442368 * 2); u16* sc2 = (u16*)alloc(442368 * 2);
  u16* m12 = (u16*)alloc(5308416L * 2);
  u16* m22 = (u16*)alloc(5308416L * 2);

  auto rp = [&](const float* W, u16* Wb, int OC, int IC, int NT) {
    long tot = (long)OC * IC * NT;
    k_repack_bf<<<(int)((tot + 255) / 256), 256, 0, stream>>>(W, Wb, ilg(OC), ilg(IC), NT, tot);
  };
  rp(tq_w, tq2, 128, 128, 3);  rp(tk_w, tk2, 128, 128, 3);
  rp(tv_w, tv2, 128, 128, 3);  rp(tp_w, tp2, 128, 128, 3);
  rp(sq_w, sq2, 128, 128, 27); rp(sk_w, sk2, 128, 128, 27);
  rp(sv_w, sv2, 128, 128, 27); rp(sp_w, sp2, 128, 128, 27);
  rp(sf_w, sf2, 128, 128, 27); rp(sc_w, sc2, 128, 128, 27);
  rp(m1_w, m12, 512, 128, 81); rp(m2_w, m22, 128, 512, 81);

  auto conv = [&](const u16* Xp, const u16* Wp, const float* Bp, void* Yp,
                  int M, int IC, int OC, int mode, int NT,
                  int Do, int Ho, int Wo, int Li, int Di, int Hi, int Wi,
                  int sL, int sD, int sH, int sW, int flags) {
    bool big = ((long)(M / 128) * (OC / 64) >= 400) && (M % 128 == 0);
    int lgWo = ilg(Wo), lgHo = ilg(Ho), lgDo = ilg(Do);
    int lgWi = ilg(Wi), lgHi = ilg(Hi), lgDi = ilg(Di);
    if (big) {
      dim3 g(M / 128, OC / 64);
      k_conv_mfma<128><<<g, 256, 0, stream>>>(Xp, Wp, Bp, Yp, M, IC, OC, mode, NT,
                                              lgWo, lgHo, lgDo, lgWi, lgHi, lgDi,
                                              Li, Di, Hi, Wi, sL, sD, sH, sW, flags);
    } else {
      dim3 g((M + 63) / 64, OC / 64);
      k_conv_mfma<64><<<g, 256, 0, stream>>>(Xp, Wp, Bp, Yp, M, IC, OC, mode, NT,
                                             lgWo, lgHo, lgDo, lgWi, lgHi, lgDi,
                                             Li, Di, Hi, Wi, sL, sD, sH, sW, flags);
    }
  };

  k_transpose_in<<<8192, 256, 0, stream>>>(x, X0);

  // ---- TLG branch ----
  k_ln_f2b<<<4096, 256, 0, stream>>>(X0, n1_w, n1_b, XN, 16384);
  conv(XN, tq2, tq_b, Qb, 16384, 128, 128, 0, 3, 16, 16, 16, 4, 16, 16, 16, 1, 1, 1, 1, 4);
  conv(XN, tk2, tk_b, Kb, 16384, 128, 128, 0, 3, 16, 16, 16, 4, 16, 16, 16, 1, 1, 1, 1, 4);
  conv(XN, tv2, tv_b, Vb, 16384, 128, 128, 0, 3, 16, 16, 16, 4, 16, 16, 16, 1, 1, 1, 1, 4);
  k_tlg_attn<<<4096, 256, 0, stream>>>(Qb, Kb, Vb, Yb);
  conv(Yb, tp2, tp_b, X0, 16384, 128, 128, 0, 3, 16, 16, 16, 4, 16, 16, 16, 1, 1, 1, 1, 1);

  // ---- SLG branch ----
  k_ln_f2b<<<4096, 256, 0, stream>>>(X0, n2_w, n2_b, XN, 16384);
  conv(XN, sq2, sq_b, Qb, 16384, 128, 128, 1, 27, 16, 16, 16, 4, 16, 16, 16, 1, 1, 1, 1, 4);
  conv(XN, sc2, sc_b, XC, 8,    128, 128, 1, 27, 2, 2, 2,   4, 16, 16, 16, 4, 8, 8, 8, 4);
  conv(XN, sf2, sf_b, XF, 1024, 128, 128, 1, 27, 8, 8, 8,   4, 16, 16, 16, 2, 2, 2, 2, 4);
  conv(XC, sk2, sk_b, Kf,            8,    128, 128, 1, 27, 2, 2, 2, 1, 2, 2, 2, 1, 1, 1, 1, 0);
  conv(XF, sk2, sk_b, Kf + 8 * 128,  1024, 128, 128, 1, 27, 8, 8, 8, 2, 8, 8, 8, 1, 1, 1, 1, 0);
  conv(XC, sv2, sv_b, Vf,            8,    128, 128, 1, 27, 2, 2, 2, 1, 2, 2, 2, 1, 1, 1, 1, 0);
  conv(XF, sv2, sv_b, Vf + 8 * 128,  1024, 128, 128, 1, 27, 8, 8, 8, 2, 8, 8, 8, 1, 1, 1, 1, 0);
  k_ln_f2b<<<258, 256, 0, stream>>>(Kf, sn_w, sn_b, Kb, 1032);
  k_ln_f2b<<<258, 256, 0, stream>>>(Vf, sn_w, sn_b, Vb, 1032);
  k_pack_kh<<<516, 256, 0, stream>>>(Kb, Kh);
  k_pack_vt<<<516, 256, 0, stream>>>(Vb, Vt);
  k_slg_flash<<<2048, 256, 0, stream>>>(Qb, Kh, Vt, Yb);
  conv(Yb, sp2, sp_b, X0, 16384, 128, 128, 1, 27, 16, 16, 16, 4, 16, 16, 16, 1, 1, 1, 1, 1);

  // ---- MLP branch ----
  k_ln_f2b<<<4096, 256, 0, stream>>>(X0, n3_w, n3_b, XN, 16384);
  conv(XN, m12, m1_b, H, 16384, 128, 512, 2, 81, 16, 16, 16, 4, 16, 16, 16, 1, 1, 1, 1, 6);
  conv(H, m22, m2_b, X0, 16384, 512, 128, 2, 81, 16, 16, 16, 4, 16, 16, 16, 1, 1, 1, 1, 1);

  k_transpose_out<<<8192, 256, 0, stream>>>(X0, (float*)d_out);
}

// Round 4
// 1403.585 us; speedup vs baseline: 6.5874x; 1.1890x over previous
//
#include <hip/hip_runtime.h>

typedef unsigned short u16;
typedef __attribute__((ext_vector_type(8))) short bf16x8;
typedef __attribute__((ext_vector_type(4))) float f32x4;

#define PITCH 40   // old kernel LDS pitch (shorts)
#define SQP 34     // square-kernel LDS pitch: 17 dwords, odd -> conflict-free stores

__device__ __forceinline__ u16 f2bf(float f) {
  union { float f; unsigned u; } v; v.f = f;
  unsigned r = v.u + 0x7fffu + ((v.u >> 16) & 1u);
  return (u16)(r >> 16);
}
__device__ __forceinline__ float bf2f(u16 h) {
  union { unsigned u; float f; } v; v.u = ((unsigned)h) << 16;
  return v.f;
}
__device__ __forceinline__ float4 load4bf(const u16* p) {
  ushort4 h = *(const ushort4*)p;
  return make_float4(bf2f(h.x), bf2f(h.y), bf2f(h.z), bf2f(h.w));
}

// ---------------- transpose (l,c,d,h,w) -> token-major [n=(l,d,h,w), c] fp32 ----------------
__global__ __launch_bounds__(256) void k_transpose_in(const float* __restrict__ x,
                                                      float* __restrict__ xt) {
  int idx = blockIdx.x * 256 + threadIdx.x;
  int c = idx & 127;
  int n = idx >> 7;
  int l = n >> 12;
  int s = n & 4095;
  xt[idx] = x[((l * 128 + c) << 12) + s];
}

__global__ __launch_bounds__(256) void k_transpose_out(const float* __restrict__ xt,
                                                       float* __restrict__ out) {
  int idx = blockIdx.x * 256 + threadIdx.x;
  int s = idx & 4095;
  int c = (idx >> 12) & 127;
  int l = idx >> 19;
  out[idx] = xt[(((l << 12) | s) << 7) + c];
}

// ---------------- layernorm fp32 in -> bf16 out, one wave per row ----------------
__global__ __launch_bounds__(256) void k_ln_f2b(const float* __restrict__ X,
                                                const float* __restrict__ g,
                                                const float* __restrict__ b,
                                                u16* __restrict__ Y, int M) {
  int n = blockIdx.x * 4 + (threadIdx.x >> 6);
  if (n >= M) return;
  int lane = threadIdx.x & 63;
  const float* row = X + (long)n * 128;
  float2 v = *(const float2*)(row + lane * 2);
  float s = v.x + v.y;
#pragma unroll
  for (int o = 32; o > 0; o >>= 1) s += __shfl_xor(s, o);
  float mu = s * (1.0f / 128.0f);
  float dx = v.x - mu, dy = v.y - mu;
  float q = dx * dx + dy * dy;
#pragma unroll
  for (int o = 32; o > 0; o >>= 1) q += __shfl_xor(q, o);
  float rs = rsqrtf(q * (1.0f / 128.0f) + 1e-5f);
  float2 gv = *(const float2*)(g + lane * 2);
  float2 bv = *(const float2*)(b + lane * 2);
  ushort2 o2;
  o2.x = f2bf(dx * rs * gv.x + bv.x);
  o2.y = f2bf(dy * rs * gv.y + bv.y);
  *(ushort2*)(Y + (long)n * 128 + lane * 2) = o2;
}

// ---------------- weight repack: W[oc][ic][tap] fp32 -> Wb[tap][oc][ic] bf16 ----------------
__global__ __launch_bounds__(256) void k_repack_bf(const float* __restrict__ W,
                                                   u16* __restrict__ Wb,
                                                   int lgOC, int lgIC, int NT, long tot) {
  long idx = (long)blockIdx.x * 256 + threadIdx.x;
  if (idx >= tot) return;
  int ic = (int)(idx & ((1 << lgIC) - 1));
  long r = idx >> lgIC;
  int oc = (int)(r & ((1 << lgOC) - 1));
  int t = (int)(r >> lgOC);
  Wb[idx] = f2bf(W[(((long)oc << lgIC) | ic) * NT + t]);
}

// ---------------- small conv-as-gather-GEMM (64/128 x 64 tile) ----------------
// flags: 1=ACC into fp32 Y, 2=RELU, 4=bf16 out (else fp32 out)
template <int MT>
__global__ __launch_bounds__(256) void k_conv_mfma(
    const u16* __restrict__ X, const u16* __restrict__ W3,
    const float* __restrict__ bias, void* __restrict__ Yv,
    int M, int IC, int OC, int mode, int NT,
    int lgWo, int lgHo, int lgDo,
    int lgWi, int lgHi, int lgDi,
    int Li, int Di, int Hi, int Wi,
    int sL, int sD, int sH, int sW, int flags) {
  __shared__ u16 As[MT * PITCH];
  __shared__ u16 Bs[64 * PITCH];
  constexpr int NA = MT / 64;
  int tid = threadIdx.x;
  int wave = tid >> 6, lane = tid & 63;
  int quad = lane >> 4, l15 = lane & 15;
  int m0 = blockIdx.x * MT;
  int oc0 = blockIdx.y * 64;

  int srl = (MT == 128) ? (tid >> 1) : (tid >> 2);
  int sao = (MT == 128) ? ((tid & 1) * 8) : ((tid & 3) * 8);
  int sboc = tid >> 2, sbo = (tid & 3) * 8;

  int sm = m0 + srl;
  bool mv = sm < M;
  int w = sm & ((1 << lgWo) - 1);
  int h = (sm >> lgWo) & ((1 << lgHo) - 1);
  int d = (sm >> (lgWo + lgHo)) & ((1 << lgDo) - 1);
  int l = sm >> (lgWo + lgHo + lgDo);

  int c0 = 0, c1 = 0, c2 = 0, c3 = 0;
  auto comp_nb = [&]() -> long {
    if (!mv) return -1;
    int li, di, hi, wi; bool ok;
    if (mode == 0) {
      int dl = c0 - 1;
      int ll = (l & 1) + dl;
      ok = (ll >= 0 && ll < 2);
      li = l + dl; di = d; hi = h; wi = w;
    } else if (mode == 1) {
      li = l * sL; di = d * sD + c2 - 1; hi = h * sH + c1 - 1; wi = w * sW + c0 - 1;
      ok = ((unsigned)di < (unsigned)Di) && ((unsigned)hi < (unsigned)Hi) &&
           ((unsigned)wi < (unsigned)Wi);
    } else {
      li = l + c3 - 1; di = d + c2 - 1; hi = h + c1 - 1; wi = w + c0 - 1;
      ok = ((unsigned)li < (unsigned)Li) && ((unsigned)di < (unsigned)Di) &&
           ((unsigned)hi < (unsigned)Hi) && ((unsigned)wi < (unsigned)Wi);
    }
    if (!ok) return -1;
    return ((((long)((li << lgDi) + di) << lgHi) + hi) << lgWi) + wi;
  };

  long nb = comp_nb();
  const u16* wt = W3 + (long)(oc0 + sboc) * IC + sbo;
  long wstep = (long)OC * IC;
  int kmask = (IC >> 5) - 1;
  int total = NT * (IC >> 5);

  const bf16x8 Z = {0, 0, 0, 0, 0, 0, 0, 0};
  bf16x8 ra0 = Z, ra1 = Z, rb;
  if (nb >= 0) {
    const u16* p = X + nb * IC + sao;
    ra0 = *(const bf16x8*)p;
    if constexpr (MT == 128) ra1 = *(const bf16x8*)(p + 16);
  }
  rb = *(const bf16x8*)wt;

  f32x4 acc[NA][4];
#pragma unroll
  for (int i = 0; i < NA; ++i)
#pragma unroll
    for (int j = 0; j < 4; ++j) acc[i][j] = {0.f, 0.f, 0.f, 0.f};

  int wrow = wave * (MT / 4);

  for (int ks = 0; ks < total; ++ks) {
    __syncthreads();
    *(bf16x8*)&As[srl * PITCH + sao] = ra0;
    if constexpr (MT == 128) *(bf16x8*)&As[srl * PITCH + sao + 16] = ra1;
    *(bf16x8*)&Bs[sboc * PITCH + sbo] = rb;
    __syncthreads();
    int ksn = ks + 1;
    if (ksn < total) {
      int k0n = (ksn & kmask) << 5;
      if ((ksn & kmask) == 0) {
        wt += wstep;
        if (++c0 == 3) { c0 = 0; if (++c1 == 3) { c1 = 0; if (++c2 == 3) { c2 = 0; ++c3; } } }
        nb = comp_nb();
      }
      ra0 = Z; ra1 = Z;
      if (nb >= 0) {
        const u16* p = X + nb * IC + k0n + sao;
        ra0 = *(const bf16x8*)p;
        if constexpr (MT == 128) ra1 = *(const bf16x8*)(p + 16);
      }
      rb = *(const bf16x8*)(wt + k0n);
    }
    bf16x8 a0 = *(const bf16x8*)&As[(wrow + l15) * PITCH + quad * 8];
    bf16x8 a1;
    if constexpr (MT == 128) a1 = *(const bf16x8*)&As[(wrow + 16 + l15) * PITCH + quad * 8];
#pragma unroll
    for (int j = 0; j < 4; ++j) {
      bf16x8 b = *(const bf16x8*)&Bs[(j * 16 + l15) * PITCH + quad * 8];
      acc[0][j] = __builtin_amdgcn_mfma_f32_16x16x32_bf16(a0, b, acc[0][j], 0, 0, 0);
      if constexpr (MT == 128)
        acc[1][j] = __builtin_amdgcn_mfma_f32_16x16x32_bf16(a1, b, acc[1][j], 0, 0, 0);
    }
  }

  int col = oc0 + l15;
#pragma unroll
  for (int j = 0; j < 4; ++j) {
    float bj = bias[col + j * 16];
#pragma unroll
    for (int i = 0; i < NA; ++i) {
      int rbase = m0 + wrow + i * 16 + quad * 4;
#pragma unroll
      for (int r = 0; r < 4; ++r) {
        int row = rbase + r;
        if (row >= M) continue;
        float v = acc[i][j][r] + bj;
        if (flags & 2) v = fmaxf(v, 0.f);
        long off = (long)row * OC + col + j * 16;
        if (flags & 4) {
          ((u16*)Yv)[off] = f2bf(v);
        } else if (flags & 1) {
          ((float*)Yv)[off] += v;
        } else {
          ((float*)Yv)[off] = v;
        }
      }
    }
  }
}

// ---------------- big conv-as-gather-GEMM: 128x128 tile, 64x64 per wave ----------------
// Optional split-K over taps via blockIdx.z (NSPLIT>1 -> raw fp32 partials into SP).
// flags (NSPLIT==1 only): 1=ACC fp32, 2=RELU, 4=bf16 out
__global__ __launch_bounds__(256) void k_conv_sq(
    const u16* __restrict__ X, const u16* __restrict__ W3,
    const float* __restrict__ bias, void* __restrict__ Yv, float* __restrict__ SP,
    int M, int IC, int OC, int mode, int NT, int NSPLIT,
    int lgWo, int lgHo, int lgDo,
    int lgWi, int lgHi, int lgDi,
    int Li, int Di, int Hi, int Wi,
    int sL, int sD, int sH, int sW, int flags) {
  __shared__ u16 As[128 * SQP];
  __shared__ u16 Bs[128 * SQP];
  int tid = threadIdx.x;
  int wave = tid >> 6, lane = tid & 63;
  int quad = lane >> 4, l15 = lane & 15;
  int m0 = blockIdx.x * 128, oc0 = blockIdx.y * 128;
  int mi = wave & 1, ni = wave >> 1;

  int tap_per = (NT + NSPLIT - 1) / NSPLIT;
  int t0 = blockIdx.z * tap_per;
  int t1 = min(NT, t0 + tap_per);
  int kc = IC >> 5;
  int kmask = kc - 1;
  int total = (t1 - t0) * kc;

  int srl = tid >> 1, sao = (tid & 1) * 16;  // A: row, 16-ch half
  int sm = m0 + srl;
  bool mv = sm < M;
  int w = sm & ((1 << lgWo) - 1);
  int h = (sm >> lgWo) & ((1 << lgHo) - 1);
  int d = (sm >> (lgWo + lgHo)) & ((1 << lgDo) - 1);
  int l = sm >> (lgWo + lgHo + lgDo);

  int c0 = t0 % 3, c1 = (t0 / 3) % 3, c2 = (t0 / 9) % 3, c3 = t0 / 27;
  auto comp_nb = [&]() -> long {
    if (!mv) return -1;
    int li, di, hi, wi; bool ok;
    if (mode == 0) {
      int dl = c0 - 1;
      int ll = (l & 1) + dl;
      ok = (ll >= 0 && ll < 2);
      li = l + dl; di = d; hi = h; wi = w;
    } else if (mode == 1) {
      li = l * sL; di = d * sD + c2 - 1; hi = h * sH + c1 - 1; wi = w * sW + c0 - 1;
      ok = ((unsigned)di < (unsigned)Di) && ((unsigned)hi < (unsigned)Hi) &&
           ((unsigned)wi < (unsigned)Wi);
    } else {
      li = l + c3 - 1; di = d + c2 - 1; hi = h + c1 - 1; wi = w + c0 - 1;
      ok = ((unsigned)li < (unsigned)Li) && ((unsigned)di < (unsigned)Di) &&
           ((unsigned)hi < (unsigned)Hi) && ((unsigned)wi < (unsigned)Wi);
    }
    if (!ok) return -1;
    return ((((long)((li << lgDi) + di) << lgHi) + hi) << lgWi) + wi;
  };

  long nb = comp_nb();
  const u16* wt = W3 + ((long)t0 * OC + oc0 + srl) * IC + sao;
  long wstep = (long)OC * IC;

  const bf16x8 Z = {0, 0, 0, 0, 0, 0, 0, 0};
  bf16x8 ra0 = Z, ra1 = Z, rb0, rb1;
  if (nb >= 0) {
    const u16* p = X + nb * IC + sao;
    ra0 = *(const bf16x8*)p;
    ra1 = *(const bf16x8*)(p + 8);
  }
  rb0 = *(const bf16x8*)wt;
  rb1 = *(const bf16x8*)(wt + 8);

  f32x4 acc[4][4];
#pragma unroll
  for (int i = 0; i < 4; ++i)
#pragma unroll
    for (int j = 0; j < 4; ++j) acc[i][j] = {0.f, 0.f, 0.f, 0.f};

  for (int ks = 0; ks < total; ++ks) {
    __syncthreads();
    *(bf16x8*)&As[srl * SQP + sao] = ra0;
    *(bf16x8*)&As[srl * SQP + sao + 8] = ra1;
    *(bf16x8*)&Bs[srl * SQP + sao] = rb0;
    *(bf16x8*)&Bs[srl * SQP + sao + 8] = rb1;
    __syncthreads();
    int ksn = ks + 1;
    if (ksn < total) {
      int k0n = (ksn & kmask) << 5;
      if ((ksn & kmask) == 0) {
        wt += wstep;
        if (++c0 == 3) { c0 = 0; if (++c1 == 3) { c1 = 0; if (++c2 == 3) { c2 = 0; ++c3; } } }
        nb = comp_nb();
      }
      ra0 = Z; ra1 = Z;
      if (nb >= 0) {
        const u16* p = X + nb * IC + k0n + sao;
        ra0 = *(const bf16x8*)p;
        ra1 = *(const bf16x8*)(p + 8);
      }
      rb0 = *(const bf16x8*)(wt + k0n);
      rb1 = *(const bf16x8*)(wt + k0n + 8);
    }
    bf16x8 af[4], bf[4];
#pragma unroll
    for (int i = 0; i < 4; ++i)
      af[i] = *(const bf16x8*)&As[(mi * 64 + i * 16 + l15) * SQP + quad * 8];
#pragma unroll
    for (int j = 0; j < 4; ++j)
      bf[j] = *(const bf16x8*)&Bs[(ni * 64 + j * 16 + l15) * SQP + quad * 8];
#pragma unroll
    for (int i = 0; i < 4; ++i)
#pragma unroll
      for (int j = 0; j < 4; ++j)
        acc[i][j] = __builtin_amdgcn_mfma_f32_16x16x32_bf16(af[i], bf[j], acc[i][j], 0, 0, 0);
  }

  // epilogue: C/D layout col=l15, row=quad*4+r
  if (NSPLIT > 1) {
    float* out = SP + (long)blockIdx.z * M * OC;
#pragma unroll
    for (int j = 0; j < 4; ++j) {
      int c = oc0 + ni * 64 + j * 16 + l15;
#pragma unroll
      for (int i = 0; i < 4; ++i) {
        int rbase = m0 + mi * 64 + i * 16 + quad * 4;
#pragma unroll
        for (int r = 0; r < 4; ++r) {
          int row = rbase + r;
          if (row < M) out[(long)row * OC + c] = acc[i][j][r];
        }
      }
    }
  } else {
#pragma unroll
    for (int j = 0; j < 4; ++j) {
      int c = oc0 + ni * 64 + j * 16 + l15;
      float bj = bias[c];
#pragma unroll
      for (int i = 0; i < 4; ++i) {
        int rbase = m0 + mi * 64 + i * 16 + quad * 4;
#pragma unroll
        for (int r = 0; r < 4; ++r) {
          int row = rbase + r;
          if (row >= M) continue;
          float v = acc[i][j][r] + bj;
          if (flags & 2) v = fmaxf(v, 0.f);
          long off = (long)row * OC + c;
          if (flags & 4) ((u16*)Yv)[off] = f2bf(v);
          else if (flags & 1) ((float*)Yv)[off] += v;
          else ((float*)Yv)[off] = v;
        }
      }
    }
  }
}

// ---------------- combine split-K partials: out = (sum_s SP[s]) + bias ----------------
// flags: 1=ACC fp32, 2=RELU, 4=bf16 out
__global__ __launch_bounds__(256) void k_combine(const float* __restrict__ SP,
                                                 const float* __restrict__ bias,
                                                 void* __restrict__ out,
                                                 long MOC, int lgOC, int nsplit, int flags) {
  long idx = (long)blockIdx.x * 256 + threadIdx.x;
  if (idx >= MOC) return;
  float v = bias[idx & ((1 << lgOC) - 1)];
  for (int s = 0; s < nsplit; ++s) v += SP[s * MOC + idx];
  if (flags & 2) v = fmaxf(v, 0.f);
  if (flags & 4) ((u16*)out)[idx] = f2bf(v);
  else if (flags & 1) ((float*)out)[idx] += v;
  else ((float*)out)[idx] = v;
}

// ---------------- TLG windowed cross attention: 8q x 8k per (window, head), bf16 ----------------
__global__ __launch_bounds__(256) void k_tlg_attn(const u16* __restrict__ Q,
                                                  const u16* __restrict__ K,
                                                  const u16* __restrict__ V,
                                                  u16* __restrict__ Y) {
  int gw = blockIdx.x * 4 + (threadIdx.x >> 6);
  int lane = threadIdx.x & 63;
  int head = gw & 7;
  int win = gw >> 3;
  int wB = win & 7, hB = (win >> 3) & 7, dB = (win >> 6) & 7, l = win >> 9;
  int i = lane >> 3, j = lane & 7;
  int nq = (l << 12) | ((dB * 2 + (i >> 2)) << 8) | ((hB * 2 + ((i >> 1) & 1)) << 4) |
           (wB * 2 + (i & 1));
  int lk = l ^ 2;
  int nk = (lk << 12) | ((dB * 2 + (j >> 2)) << 8) | ((hB * 2 + ((j >> 1) & 1)) << 4) |
           (wB * 2 + (j & 1));
  int hoff = head * 16;
  const u16* qp = Q + (long)nq * 128 + hoff;
  const u16* kp = K + (long)nk * 128 + hoff;
  float s = 0.f;
#pragma unroll
  for (int t = 0; t < 16; t += 4) {
    float4 a = load4bf(qp + t);
    float4 b = load4bf(kp + t);
    s += a.x * b.x + a.y * b.y + a.z * b.z + a.w * b.w;
  }
  s *= 0.25f;
  float mx = s;
#pragma unroll
  for (int o = 1; o < 8; o <<= 1) mx = fmaxf(mx, __shfl_xor(mx, o));
  float e = __expf(s - mx);
  float sum = e;
#pragma unroll
  for (int o = 1; o < 8; o <<= 1) sum += __shfl_xor(sum, o);
  float p = e / sum;
  const u16* vp = V + (long)nk * 128 + hoff;
  float y[16];
#pragma unroll
  for (int t = 0; t < 16; t += 4) {
    float4 vv = load4bf(vp + t);
    y[t] = p * vv.x; y[t + 1] = p * vv.y; y[t + 2] = p * vv.z; y[t + 3] = p * vv.w;
  }
#pragma unroll
  for (int o = 1; o < 8; o <<= 1) {
#pragma unroll
    for (int t = 0; t < 16; ++t) y[t] += __shfl_xor(y[t], o);
  }
  if (j == 0) {
    u16* yp = Y + (long)nq * 128 + hoff;
    u16 tmp[16];
#pragma unroll
    for (int t = 0; t < 16; ++t) tmp[t] = f2bf(y[t]);
    *(uint4*)(yp) = *(uint4*)tmp;
    *(uint4*)(yp + 8) = *(uint4*)(tmp + 8);
  }
}

// ---------------- SLG K/V repack for flash attn ----------------
__global__ __launch_bounds__(256) void k_pack_kh(const u16* __restrict__ Kin,
                                                 u16* __restrict__ Kh) {
  int idx = blockIdx.x * 256 + threadIdx.x;
  if (idx >= 8 * 1032 * 16) return;
  int d = idx & 15;
  int r = idx >> 4;
  int k = r % 1032, h = r / 1032;
  Kh[idx] = Kin[k * 128 + h * 16 + d];
}
__global__ __launch_bounds__(256) void k_pack_vt(const u16* __restrict__ Vin,
                                                 u16* __restrict__ Vt) {
  int idx = blockIdx.x * 256 + threadIdx.x;
  if (idx >= 8 * 16 * 1032) return;
  int k = idx % 1032;
  int r = idx / 1032;
  int d = r & 15, h = r >> 4;
  Vt[idx] = Vin[k * 128 + h * 16 + d];
}

// ---------------- SLG MFMA flash attention ----------------
__global__ __launch_bounds__(256) void k_slg_flash(const u16* __restrict__ Q,
                                                   const u16* __restrict__ Kh,
                                                   const u16* __restrict__ Vt,
                                                   u16* __restrict__ Y) {
  constexpr int NK = 1032;
  constexpr int NTILE = 17;
  __shared__ __align__(16) u16 Ks[64 * 24];
  __shared__ __align__(16) u16 Vs[16 * 72];
  __shared__ __align__(16) u16 Ps[4][16 * 72];
  int tid = threadIdx.x;
  int wave = tid >> 6, lane = tid & 63;
  int quad = lane >> 4, l15 = lane & 15;
  int h = blockIdx.x & 7;
  int q0 = (blockIdx.x >> 3) * 64 + wave * 16;

  const bf16x8 Zb = {0, 0, 0, 0, 0, 0, 0, 0};
  bf16x8 qf = Zb;
  if (quad < 2) qf = *(const bf16x8*)(Q + (long)(q0 + l15) * 128 + h * 16 + quad * 8);

  const u16* Kbase = Kh + (long)h * NK * 16;
  const u16* Vbase = Vt + (long)h * 16 * NK;

  float mrow[4], lrow[4];
  f32x4 oacc = {0.f, 0.f, 0.f, 0.f};
#pragma unroll
  for (int r = 0; r < 4; ++r) { mrow[r] = -1e30f; lrow[r] = 0.f; }

  int skey = tid >> 2, sch = (tid & 3) * 4;
  int svd = tid >> 4, svc = (tid & 15) * 4;

  for (int t = 0; t < NTILE; ++t) {
    int k0 = t * 64;
    __syncthreads();
    {
      short4 v = {0, 0, 0, 0};
      int key = k0 + skey;
      if (key < NK) v = *(const short4*)(Kbase + key * 16 + sch);
      *(short4*)&Ks[skey * 24 + sch] = v;
    }
    {
      short4 v = {0, 0, 0, 0};
      int colb = k0 + svc;
      if (colb < NK) v = *(const short4*)(Vbase + svd * NK + colb);
      *(short4*)&Vs[svd * 72 + svc] = v;
    }
    __syncthreads();

    f32x4 s[4];
#pragma unroll
    for (int sub = 0; sub < 4; ++sub) {
      bf16x8 b = Zb;
      if (quad < 2) b = *(const bf16x8*)&Ks[(sub * 16 + l15) * 24 + quad * 8];
      f32x4 zero = {0.f, 0.f, 0.f, 0.f};
      s[sub] = __builtin_amdgcn_mfma_f32_16x16x32_bf16(qf, b, zero, 0, 0, 0);
    }
    float pv[4][4];
    float tmax[4] = {-1e30f, -1e30f, -1e30f, -1e30f};
#pragma unroll
    for (int sub = 0; sub < 4; ++sub) {
      int key = k0 + sub * 16 + l15;
      bool valid = key < NK;
#pragma unroll
      for (int r = 0; r < 4; ++r) {
        float sv = valid ? s[sub][r] * 0.25f : -1e30f;
        pv[sub][r] = sv;
        tmax[r] = fmaxf(tmax[r], sv);
      }
    }
#pragma unroll
    for (int o = 1; o < 16; o <<= 1)
#pragma unroll
      for (int r = 0; r < 4; ++r) tmax[r] = fmaxf(tmax[r], __shfl_xor(tmax[r], o));

    float al[4], tsum[4] = {0.f, 0.f, 0.f, 0.f};
#pragma unroll
    for (int r = 0; r < 4; ++r) {
      float mn = fmaxf(mrow[r], tmax[r]);
      al[r] = __expf(mrow[r] - mn);
      mrow[r] = mn;
    }
#pragma unroll
    for (int sub = 0; sub < 4; ++sub)
#pragma unroll
      for (int r = 0; r < 4; ++r) {
        float pe = __expf(pv[sub][r] - mrow[r]);
        tsum[r] += pe;
        Ps[wave][(quad * 4 + r) * 72 + sub * 16 + l15] = f2bf(pe);
      }
#pragma unroll
    for (int o = 1; o < 16; o <<= 1)
#pragma unroll
      for (int r = 0; r < 4; ++r) tsum[r] += __shfl_xor(tsum[r], o);
#pragma unroll
    for (int r = 0; r < 4; ++r) {
      lrow[r] = lrow[r] * al[r] + tsum[r];
      oacc[r] *= al[r];
    }
    bf16x8 pa0 = *(const bf16x8*)&Ps[wave][l15 * 72 + quad * 8];
    bf16x8 pa1 = *(const bf16x8*)&Ps[wave][l15 * 72 + 32 + quad * 8];
    bf16x8 vb0 = *(const bf16x8*)&Vs[l15 * 72 + quad * 8];
    bf16x8 vb1 = *(const bf16x8*)&Vs[l15 * 72 + 32 + quad * 8];
    oacc = __builtin_amdgcn_mfma_f32_16x16x32_bf16(pa0, vb0, oacc, 0, 0, 0);
    oacc = __builtin_amdgcn_mfma_f32_16x16x32_bf16(pa1, vb1, oacc, 0, 0, 0);
  }

#pragma unroll
  for (int r = 0; r < 4; ++r) {
    float inv = 1.0f / lrow[r];
    Y[(long)(q0 + quad * 4 + r) * 128 + h * 16 + l15] = f2bf(oacc[r] * inv);
  }
}

static inline int ilg(int v) { int r = 0; while ((1 << r) < v) ++r; return r; }

extern "C" void kernel_launch(void* const* d_in, const int* in_sizes, int n_in,
                              void* d_out, int out_size, void* d_ws, size_t ws_size,
                              hipStream_t stream) {
  (void)in_sizes; (void)n_in; (void)out_size; (void)ws_size;
  const float* x    = (const float*)d_in[0];
  const float* n1_w = (const float*)d_in[1];  const float* n1_b = (const float*)d_in[2];
  const float* n2_w = (const float*)d_in[3];  const float* n2_b = (const float*)d_in[4];
  const float* n3_w = (const float*)d_in[5];  const float* n3_b = (const float*)d_in[6];
  const float* sn_w = (const float*)d_in[7];  const float* sn_b = (const float*)d_in[8];
  const float* tq_w = (const float*)d_in[9];  const float* tq_b = (const float*)d_in[10];
  const float* tk_w = (const float*)d_in[11]; const float* tk_b = (const float*)d_in[12];
  const float* tv_w = (const float*)d_in[13]; const float* tv_b = (const float*)d_in[14];
  const float* tp_w = (const float*)d_in[15]; const float* tp_b = (const float*)d_in[16];
  const float* sq_w = (const float*)d_in[17]; const float* sq_b = (const float*)d_in[18];
  const float* sk_w = (const float*)d_in[19]; const float* sk_b = (const float*)d_in[20];
  const float* sv_w = (const float*)d_in[21]; const float* sv_b = (const float*)d_in[22];
  const float* sp_w = (const float*)d_in[23]; const float* sp_b = (const float*)d_in[24];
  const float* sf_w = (const float*)d_in[25]; const float* sf_b = (const float*)d_in[26];
  const float* sc_w = (const float*)d_in[27]; const float* sc_b = (const float*)d_in[28];
  const float* m1_w = (const float*)d_in[29]; const float* m1_b = (const float*)d_in[30];
  const float* m2_w = (const float*)d_in[31]; const float* m2_b = (const float*)d_in[32];

  char* p = (char*)d_ws;
  auto alloc = [&](size_t bytes) { char* r = p; p += (bytes + 255) & ~(size_t)255; return r; };
  const long N = 16384;
  float* X0 = (float*)alloc(N * 128 * 4);
  u16* XN = (u16*)alloc(N * 128 * 2);
  u16* Qb = (u16*)alloc(N * 128 * 2);
  u16* Kb = (u16*)alloc(N * 128 * 2);
  u16* Vb = (u16*)alloc(N * 128 * 2);
  u16* Yb = (u16*)alloc(N * 128 * 2);
  u16* H  = (u16*)alloc(N * 512 * 2);
  u16* XC = (u16*)alloc(8 * 128 * 2);
  u16* XF = (u16*)alloc(1024 * 128 * 2);
  float* Kf = (float*)alloc(1032 * 128 * 4);
  float* Vf = (float*)alloc(1032 * 128 * 4);
  u16* Kh = (u16*)alloc(8 * 1032 * 16 * 2);
  u16* Vt = (u16*)alloc(8 * 16 * 1032 * 2);
  float* SPb = (float*)alloc(4L * N * 128 * 4);  // split-K partials
  u16* tq2 = (u16*)alloc(49152 * 2);  u16* tk2 = (u16*)alloc(49152 * 2);
  u16* tv2 = (u16*)alloc(49152 * 2);  u16* tp2 = (u16*)alloc(49152 * 2);
  u16* sq2 = (u16*)alloc(442368 * 2); u16* sk2 = (u16*)alloc(442368 * 2);
  u16* sv2 = (u16*)alloc(442368 * 2); u16* sp2 = (u16*)alloc(442368 * 2);
  u16* sf2 = (u16*)alloc(442368 * 2); u16* sc2 = (u16*)alloc(442368 * 2);
  u16* m12 = (u16*)alloc(5308416L * 2);
  u16* m22 = (u16*)alloc(5308416L * 2);

  auto rp = [&](const float* W, u16* Wb, int OC, int IC, int NT) {
    long tot = (long)OC * IC * NT;
    k_repack_bf<<<(int)((tot + 255) / 256), 256, 0, stream>>>(W, Wb, ilg(OC), ilg(IC), NT, tot);
  };
  rp(tq_w, tq2, 128, 128, 3);  rp(tk_w, tk2, 128, 128, 3);
  rp(tv_w, tv2, 128, 128, 3);  rp(tp_w, tp2, 128, 128, 3);
  rp(sq_w, sq2, 128, 128, 27); rp(sk_w, sk2, 128, 128, 27);
  rp(sv_w, sv2, 128, 128, 27); rp(sp_w, sp2, 128, 128, 27);
  rp(sf_w, sf2, 128, 128, 27); rp(sc_w, sc2, 128, 128, 27);
  rp(m1_w, m12, 512, 128, 81); rp(m2_w, m22, 128, 512, 81);

  // small/odd-shape convs -> k_conv_mfma
  auto conv = [&](const u16* Xp, const u16* Wp, const float* Bp, void* Yp,
                  int M, int IC, int OC, int mode, int NT,
                  int Do, int Ho, int Wo, int Li, int Di, int Hi, int Wi,
                  int sL, int sD, int sH, int sW, int flags) {
    bool big = ((long)(M / 128) * (OC / 64) >= 256) && (M % 128 == 0);
    int lgWo = ilg(Wo), lgHo = ilg(Ho), lgDo = ilg(Do);
    int lgWi = ilg(Wi), lgHi = ilg(Hi), lgDi = ilg(Di);
    if (big) {
      dim3 g(M / 128, OC / 64);
      k_conv_mfma<128><<<g, 256, 0, stream>>>(Xp, Wp, Bp, Yp, M, IC, OC, mode, NT,
                                              lgWo, lgHo, lgDo, lgWi, lgHi, lgDi,
                                              Li, Di, Hi, Wi, sL, sD, sH, sW, flags);
    } else {
      dim3 g((M + 63) / 64, OC / 64);
      k_conv_mfma<64><<<g, 256, 0, stream>>>(Xp, Wp, Bp, Yp, M, IC, OC, mode, NT,
                                             lgWo, lgHo, lgDo, lgWi, lgHi, lgDi,
                                             Li, Di, Hi, Wi, sL, sD, sH, sW, flags);
    }
  };
  // big GEMMs -> square tile + optional split-K
  auto conv_sq = [&](const u16* Xp, const u16* Wp, const float* Bp, void* Yp,
                     int M, int IC, int OC, int mode, int NT, int nsplit,
                     int flags) {
    dim3 g(M / 128, OC / 128, nsplit);
    k_conv_sq<<<g, 256, 0, stream>>>(Xp, Wp, Bp, Yp, SPb, M, IC, OC, mode, NT, nsplit,
                                     4, 4, 4, 4, 4, 4, 4, 16, 16, 16, 1, 1, 1, 1, flags);
    if (nsplit > 1) {
      long MOC = (long)M * OC;
      k_combine<<<(int)((MOC + 255) / 256), 256, 0, stream>>>(SPb, Bp, Yp, MOC, ilg(OC),
                                                              nsplit, flags);
    }
  };

  k_transpose_in<<<8192, 256, 0, stream>>>(x, X0);

  // ---- TLG branch ----
  k_ln_f2b<<<4096, 256, 0, stream>>>(X0, n1_w, n1_b, XN, 16384);
  conv(XN, tq2, tq_b, Qb, 16384, 128, 128, 0, 3, 16, 16, 16, 4, 16, 16, 16, 1, 1, 1, 1, 4);
  conv(XN, tk2, tk_b, Kb, 16384, 128, 128, 0, 3, 16, 16, 16, 4, 16, 16, 16, 1, 1, 1, 1, 4);
  conv(XN, tv2, tv_b, Vb, 16384, 128, 128, 0, 3, 16, 16, 16, 4, 16, 16, 16, 1, 1, 1, 1, 4);
  k_tlg_attn<<<4096, 256, 0, stream>>>(Qb, Kb, Vb, Yb);
  conv(Yb, tp2, tp_b, X0, 16384, 128, 128, 0, 3, 16, 16, 16, 4, 16, 16, 16, 1, 1, 1, 1, 1);

  // ---- SLG branch ----
  k_ln_f2b<<<4096, 256, 0, stream>>>(X0, n2_w, n2_b, XN, 16384);
  conv_sq(XN, sq2, sq_b, Qb, 16384, 128, 128, 1, 27, 4, 4);       // bf16 out
  conv(XN, sc2, sc_b, XC, 8,    128, 128, 1, 27, 2, 2, 2,   4, 16, 16, 16, 4, 8, 8, 8, 4);
  conv(XN, sf2, sf_b, XF, 1024, 128, 128, 1, 27, 8, 8, 8,   4, 16, 16, 16, 2, 2, 2, 2, 4);
  conv(XC, sk2, sk_b, Kf,            8,    128, 128, 1, 27, 2, 2, 2, 1, 2, 2, 2, 1, 1, 1, 1, 0);
  conv(XF, sk2, sk_b, Kf + 8 * 128,  1024, 128, 128, 1, 27, 8, 8, 8, 2, 8, 8, 8, 1, 1, 1, 1, 0);
  conv(XC, sv2, sv_b, Vf,            8,    128, 128, 1, 27, 2, 2, 2, 1, 2, 2, 2, 1, 1, 1, 1, 0);
  conv(XF, sv2, sv_b, Vf + 8 * 128,  1024, 128, 128, 1, 27, 8, 8, 8, 2, 8, 8, 8, 1, 1, 1, 1, 0);
  k_ln_f2b<<<258, 256, 0, stream>>>(Kf, sn_w, sn_b, Kb, 1032);
  k_ln_f2b<<<258, 256, 0, stream>>>(Vf, sn_w, sn_b, Vb, 1032);
  k_pack_kh<<<516, 256, 0, stream>>>(Kb, Kh);
  k_pack_vt<<<516, 256, 0, stream>>>(Vb, Vt);
  k_slg_flash<<<2048, 256, 0, stream>>>(Qb, Kh, Vt, Yb);
  conv_sq(Yb, sp2, sp_b, X0, 16384, 128, 128, 1, 27, 4, 1);       // ACC fp32

  // ---- MLP branch ----
  k_ln_f2b<<<4096, 256, 0, stream>>>(X0, n3_w, n3_b, XN, 16384);
  conv_sq(XN, m12, m1_b, H, 16384, 128, 512, 2, 81, 1, 6);        // relu + bf16, no split
  conv_sq(H, m22, m2_b, X0, 16384, 512, 128, 2, 81, 4, 1);        // split-4, ACC fp32

  k_transpose_out<<<8192, 256, 0, stream>>>(X0, (float*)d_out);
}

// Round 5
// 1346.148 us; speedup vs baseline: 6.8685x; 1.0427x over previous
//
#include <hip/hip_runtime.h>

typedef unsigned short u16;
typedef __attribute__((ext_vector_type(8))) short bf16x8;
typedef __attribute__((ext_vector_type(4))) float f32x4;

#define PITCH 40   // small-conv kernel LDS pitch (shorts)

__device__ __forceinline__ u16 f2bf(float f) {
  union { float f; unsigned u; } v; v.f = f;
  unsigned r = v.u + 0x7fffu + ((v.u >> 16) & 1u);
  return (u16)(r >> 16);
}
__device__ __forceinline__ float bf2f(u16 h) {
  union { unsigned u; float f; } v; v.u = ((unsigned)h) << 16;
  return v.f;
}
__device__ __forceinline__ float4 load4bf(const u16* p) {
  ushort4 h = *(const ushort4*)p;
  return make_float4(bf2f(h.x), bf2f(h.y), bf2f(h.z), bf2f(h.w));
}
// async global->LDS, 16B per lane; LDS dest = wave-uniform base + lane*16
__device__ __forceinline__ void gll16(const u16* g, u16* l) {
  __builtin_amdgcn_global_load_lds(
      (const __attribute__((address_space(1))) unsigned int*)g,
      (__attribute__((address_space(3))) unsigned int*)l, 16, 0, 0);
}

// ---------------- transpose (l,c,d,h,w) -> token-major [n=(l,d,h,w), c] fp32 ----------------
__global__ __launch_bounds__(256) void k_transpose_in(const float* __restrict__ x,
                                                      float* __restrict__ xt) {
  int idx = blockIdx.x * 256 + threadIdx.x;
  int c = idx & 127;
  int n = idx >> 7;
  int l = n >> 12;
  int s = n & 4095;
  xt[idx] = x[((l * 128 + c) << 12) + s];
}

__global__ __launch_bounds__(256) void k_transpose_out(const float* __restrict__ xt,
                                                       float* __restrict__ out) {
  int idx = blockIdx.x * 256 + threadIdx.x;
  int s = idx & 4095;
  int c = (idx >> 12) & 127;
  int l = idx >> 19;
  out[idx] = xt[(((l << 12) | s) << 7) + c];
}

__global__ __launch_bounds__(128) void k_zeropage(u16* __restrict__ zp) {
  zp[threadIdx.x] = 0;
}

// ---------------- layernorm fp32 in -> bf16 out, one wave per row ----------------
__global__ __launch_bounds__(256) void k_ln_f2b(const float* __restrict__ X,
                                                const float* __restrict__ g,
                                                const float* __restrict__ b,
                                                u16* __restrict__ Y, int M) {
  int n = blockIdx.x * 4 + (threadIdx.x >> 6);
  if (n >= M) return;
  int lane = threadIdx.x & 63;
  const float* row = X + (long)n * 128;
  float2 v = *(const float2*)(row + lane * 2);
  float s = v.x + v.y;
#pragma unroll
  for (int o = 32; o > 0; o >>= 1) s += __shfl_xor(s, o);
  float mu = s * (1.0f / 128.0f);
  float dx = v.x - mu, dy = v.y - mu;
  float q = dx * dx + dy * dy;
#pragma unroll
  for (int o = 32; o > 0; o >>= 1) q += __shfl_xor(q, o);
  float rs = rsqrtf(q * (1.0f / 128.0f) + 1e-5f);
  float2 gv = *(const float2*)(g + lane * 2);
  float2 bv = *(const float2*)(b + lane * 2);
  ushort2 o2;
  o2.x = f2bf(dx * rs * gv.x + bv.x);
  o2.y = f2bf(dy * rs * gv.y + bv.y);
  *(ushort2*)(Y + (long)n * 128 + lane * 2) = o2;
}

// ---------------- weight repack: W[oc][ic][tap] fp32 -> Wb[tap][oc][ic] bf16 ----------------
__global__ __launch_bounds__(256) void k_repack_bf(const float* __restrict__ W,
                                                   u16* __restrict__ Wb,
                                                   int lgOC, int lgIC, int NT, long tot) {
  long idx = (long)blockIdx.x * 256 + threadIdx.x;
  if (idx >= tot) return;
  int ic = (int)(idx & ((1 << lgIC) - 1));
  long r = idx >> lgIC;
  int oc = (int)(r & ((1 << lgOC) - 1));
  int t = (int)(r >> lgOC);
  Wb[idx] = f2bf(W[(((long)oc << lgIC) | ic) * NT + t]);
}

// ---------------- small conv-as-gather-GEMM (64 x 64 tile) for small M ----------------
// flags: 1=ACC into fp32 Y, 2=RELU, 4=bf16 out (else fp32 out)
__global__ __launch_bounds__(256) void k_conv_mfma(
    const u16* __restrict__ X, const u16* __restrict__ W3,
    const float* __restrict__ bias, void* __restrict__ Yv,
    int M, int IC, int OC, int mode, int NT,
    int lgWo, int lgHo, int lgDo,
    int lgWi, int lgHi, int lgDi,
    int Li, int Di, int Hi, int Wi,
    int sL, int sD, int sH, int sW, int flags) {
  __shared__ u16 As[64 * PITCH];
  __shared__ u16 Bs[64 * PITCH];
  int tid = threadIdx.x;
  int wave = tid >> 6, lane = tid & 63;
  int quad = lane >> 4, l15 = lane & 15;
  int m0 = blockIdx.x * 64;
  int oc0 = blockIdx.y * 64;

  int srl = tid >> 2;
  int sao = (tid & 3) * 8;
  int sboc = tid >> 2, sbo = (tid & 3) * 8;

  int sm = m0 + srl;
  bool mv = sm < M;
  int w = sm & ((1 << lgWo) - 1);
  int h = (sm >> lgWo) & ((1 << lgHo) - 1);
  int d = (sm >> (lgWo + lgHo)) & ((1 << lgDo) - 1);
  int l = sm >> (lgWo + lgHo + lgDo);

  int c0 = 0, c1 = 0, c2 = 0, c3 = 0;
  auto comp_nb = [&]() -> long {
    if (!mv) return -1;
    int li, di, hi, wi; bool ok;
    if (mode == 0) {
      int dl = c0 - 1;
      int ll = (l & 1) + dl;
      ok = (ll >= 0 && ll < 2);
      li = l + dl; di = d; hi = h; wi = w;
    } else if (mode == 1) {
      li = l * sL; di = d * sD + c2 - 1; hi = h * sH + c1 - 1; wi = w * sW + c0 - 1;
      ok = ((unsigned)di < (unsigned)Di) && ((unsigned)hi < (unsigned)Hi) &&
           ((unsigned)wi < (unsigned)Wi);
    } else {
      li = l + c3 - 1; di = d + c2 - 1; hi = h + c1 - 1; wi = w + c0 - 1;
      ok = ((unsigned)li < (unsigned)Li) && ((unsigned)di < (unsigned)Di) &&
           ((unsigned)hi < (unsigned)Hi) && ((unsigned)wi < (unsigned)Wi);
    }
    if (!ok) return -1;
    return ((((long)((li << lgDi) + di) << lgHi) + hi) << lgWi) + wi;
  };

  long nb = comp_nb();
  const u16* wt = W3 + (long)(oc0 + sboc) * IC + sbo;
  long wstep = (long)OC * IC;
  int kmask = (IC >> 5) - 1;
  int total = NT * (IC >> 5);

  const bf16x8 Z = {0, 0, 0, 0, 0, 0, 0, 0};
  bf16x8 ra0 = Z, rb;
  if (nb >= 0) ra0 = *(const bf16x8*)(X + nb * IC + sao);
  rb = *(const bf16x8*)wt;

  f32x4 acc[4];
#pragma unroll
  for (int j = 0; j < 4; ++j) acc[j] = {0.f, 0.f, 0.f, 0.f};

  int wrow = wave * 16;

  for (int ks = 0; ks < total; ++ks) {
    __syncthreads();
    *(bf16x8*)&As[srl * PITCH + sao] = ra0;
    *(bf16x8*)&Bs[sboc * PITCH + sbo] = rb;
    __syncthreads();
    int ksn = ks + 1;
    if (ksn < total) {
      int k0n = (ksn & kmask) << 5;
      if ((ksn & kmask) == 0) {
        wt += wstep;
        if (++c0 == 3) { c0 = 0; if (++c1 == 3) { c1 = 0; if (++c2 == 3) { c2 = 0; ++c3; } } }
        nb = comp_nb();
      }
      ra0 = Z;
      if (nb >= 0) ra0 = *(const bf16x8*)(X + nb * IC + k0n + sao);
      rb = *(const bf16x8*)(wt + k0n);
    }
    bf16x8 a0 = *(const bf16x8*)&As[(wrow + l15) * PITCH + quad * 8];
#pragma unroll
    for (int j = 0; j < 4; ++j) {
      bf16x8 b = *(const bf16x8*)&Bs[(j * 16 + l15) * PITCH + quad * 8];
      acc[j] = __builtin_amdgcn_mfma_f32_16x16x32_bf16(a0, b, acc[j], 0, 0, 0);
    }
  }

  int col = oc0 + l15;
#pragma unroll
  for (int j = 0; j < 4; ++j) {
    float bj = bias[col + j * 16];
    int rbase = m0 + wrow + quad * 4;
#pragma unroll
    for (int r = 0; r < 4; ++r) {
      int row = rbase + r;
      if (row >= M) continue;
      float v = acc[j][r] + bj;
      if (flags & 2) v = fmaxf(v, 0.f);
      long off = (long)row * OC + col + j * 16;
      if (flags & 4) ((u16*)Yv)[off] = f2bf(v);
      else if (flags & 1) ((float*)Yv)[off] += v;
      else ((float*)Yv)[off] = v;
    }
  }
}

// ---------------- big conv-GEMM: 128x128 tile, global_load_lds staging ----------------
// LDS layout: [row][32 shorts], 16B chunk swizzled: physical chunk = (logical + (row>>1)) & 3.
// Invalid gather rows read from 64B zero page ZP.
// NSPLIT>1 -> raw fp32 partials into SP (combine kernel adds bias etc).
// flags (NSPLIT==1): 1=ACC fp32, 2=RELU, 4=bf16 out
__global__ __launch_bounds__(256) void k_conv_gl(
    const u16* __restrict__ X, const u16* __restrict__ W3,
    const float* __restrict__ bias, void* __restrict__ Yv, float* __restrict__ SP,
    const u16* __restrict__ ZP,
    int M, int IC, int OC, int mode, int NT, int NSPLIT,
    int lgWo, int lgHo, int lgDo,
    int lgWi, int lgHi, int lgDi,
    int Li, int Di, int Hi, int Wi,
    int sL, int sD, int sH, int sW, int flags) {
  __shared__ __align__(16) u16 As[128 * 32];
  __shared__ __align__(16) u16 Bs[128 * 32];
  int tid = threadIdx.x;
  int wave = tid >> 6, lane = tid & 63;
  int quad = lane >> 4, l15 = lane & 15;
  int m0 = blockIdx.x * 128, oc0 = blockIdx.y * 128;
  int mi = wave & 1, ni = wave >> 1;

  // staging: this thread covers rows r0 and r1 (= r0+16), chunk pc, of both A and B
  int pc = lane & 3;
  int r0 = wave * 32 + (lane >> 2);
  int r1 = r0 + 16;
  int lcA0 = (pc - (r0 >> 1)) & 3;   // logical chunk stored at slot (r0, pc)
  int lcA1 = (pc - (r1 >> 1)) & 3;
  u16* lA0 = As + wave * 1024;       // 16 rows * 32 shorts = 1024B per issue
  u16* lA1 = As + wave * 1024 + 512;
  u16* lB0 = Bs + wave * 1024;
  u16* lB1 = Bs + wave * 1024 + 512;

  // token decode for A rows
  int sm0 = m0 + r0, sm1 = m0 + r1;
  bool v0 = sm0 < M, v1 = sm1 < M;
  int w0 = sm0 & ((1 << lgWo) - 1), h0 = (sm0 >> lgWo) & ((1 << lgHo) - 1);
  int d0 = (sm0 >> (lgWo + lgHo)) & ((1 << lgDo) - 1), l0 = sm0 >> (lgWo + lgHo + lgDo);
  int w1 = sm1 & ((1 << lgWo) - 1), h1 = (sm1 >> lgWo) & ((1 << lgHo) - 1);
  int d1 = (sm1 >> (lgWo + lgHo)) & ((1 << lgDo) - 1), l1 = sm1 >> (lgWo + lgHo + lgDo);

  int tap_per = (NT + NSPLIT - 1) / NSPLIT;
  int t0 = blockIdx.z * tap_per;
  int t1 = min(NT, t0 + tap_per);
  int kc = IC >> 5, kmask = kc - 1;
  int total = (t1 - t0) * kc;

  int c0 = t0 % 3, c1 = (t0 / 3) % 3, c2 = (t0 / 9) % 3, c3 = t0 / 27;
  auto comp_nb = [&](bool mv, int w, int h, int d, int l) -> long {
    if (!mv) return -1;
    int li, di, hi, wi; bool ok;
    if (mode == 0) {
      int dl = c0 - 1;
      int ll = (l & 1) + dl;
      ok = (ll >= 0 && ll < 2);
      li = l + dl; di = d; hi = h; wi = w;
    } else if (mode == 1) {
      li = l * sL; di = d * sD + c2 - 1; hi = h * sH + c1 - 1; wi = w * sW + c0 - 1;
      ok = ((unsigned)di < (unsigned)Di) && ((unsigned)hi < (unsigned)Hi) &&
           ((unsigned)wi < (unsigned)Wi);
    } else {
      li = l + c3 - 1; di = d + c2 - 1; hi = h + c1 - 1; wi = w + c0 - 1;
      ok = ((unsigned)li < (unsigned)Li) && ((unsigned)di < (unsigned)Di) &&
           ((unsigned)hi < (unsigned)Hi) && ((unsigned)wi < (unsigned)Wi);
    }
    if (!ok) return -1;
    return ((((long)((li << lgDi) + di) << lgHi) + hi) << lgWi) + wi;
  };

  long nbA0 = comp_nb(v0, w0, h0, d0, l0);
  long nbA1 = comp_nb(v1, w1, h1, d1, l1);
  long wstep = (long)OC * IC;
  const u16* wB0 = W3 + ((long)t0 * OC + oc0 + r0) * IC + ((pc - (r0 >> 1)) & 3) * 8;
  const u16* wB1 = W3 + ((long)t0 * OC + oc0 + r1) * IC + ((pc - (r1 >> 1)) & 3) * 8;

  f32x4 acc[4][4];
#pragma unroll
  for (int i = 0; i < 4; ++i)
#pragma unroll
    for (int j = 0; j < 4; ++j) acc[i][j] = {0.f, 0.f, 0.f, 0.f};

  for (int ks = 0; ks < total; ++ks) {
    if (ks && (ks & kmask) == 0) {
      if (++c0 == 3) { c0 = 0; if (++c1 == 3) { c1 = 0; if (++c2 == 3) { c2 = 0; ++c3; } } }
      nbA0 = comp_nb(v0, w0, h0, d0, l0);
      nbA1 = comp_nb(v1, w1, h1, d1, l1);
      wB0 += wstep;
      wB1 += wstep;
    }
    int k0 = (ks & kmask) << 5;
    __syncthreads();  // all frag reads of previous tile done
    const u16* a0 = (nbA0 >= 0) ? X + nbA0 * IC + k0 + lcA0 * 8 : ZP;
    const u16* a1 = (nbA1 >= 0) ? X + nbA1 * IC + k0 + lcA1 * 8 : ZP;
    gll16(a0, lA0);
    gll16(a1, lA1);
    gll16(wB0 + k0, lB0);
    gll16(wB1 + k0, lB1);
    __syncthreads();  // vmcnt(0) drain -> LDS tile ready
    bf16x8 af[4], bf[4];
#pragma unroll
    for (int i = 0; i < 4; ++i) {
      int row = mi * 64 + i * 16 + l15;
      int pa = (quad + (row >> 1)) & 3;
      af[i] = *(const bf16x8*)&As[row * 32 + pa * 8];
    }
#pragma unroll
    for (int j = 0; j < 4; ++j) {
      int row = ni * 64 + j * 16 + l15;
      int pb = (quad + (row >> 1)) & 3;
      bf[j] = *(const bf16x8*)&Bs[row * 32 + pb * 8];
    }
#pragma unroll
    for (int i = 0; i < 4; ++i)
#pragma unroll
      for (int j = 0; j < 4; ++j)
        acc[i][j] = __builtin_amdgcn_mfma_f32_16x16x32_bf16(af[i], bf[j], acc[i][j], 0, 0, 0);
  }

  // epilogue: C/D layout col=l15, row=quad*4+r
  if (NSPLIT > 1) {
    float* out = SP + (long)blockIdx.z * M * OC;
#pragma unroll
    for (int j = 0; j < 4; ++j) {
      int c = oc0 + ni * 64 + j * 16 + l15;
#pragma unroll
      for (int i = 0; i < 4; ++i) {
        int rbase = m0 + mi * 64 + i * 16 + quad * 4;
#pragma unroll
        for (int r = 0; r < 4; ++r) {
          int row = rbase + r;
          if (row < M) out[(long)row * OC + c] = acc[i][j][r];
        }
      }
    }
  } else {
#pragma unroll
    for (int j = 0; j < 4; ++j) {
      int c = oc0 + ni * 64 + j * 16 + l15;
      float bj = bias[c];
#pragma unroll
      for (int i = 0; i < 4; ++i) {
        int rbase = m0 + mi * 64 + i * 16 + quad * 4;
#pragma unroll
        for (int r = 0; r < 4; ++r) {
          int row = rbase + r;
          if (row >= M) continue;
          float v = acc[i][j][r] + bj;
          if (flags & 2) v = fmaxf(v, 0.f);
          long off = (long)row * OC + c;
          if (flags & 4) ((u16*)Yv)[off] = f2bf(v);
          else if (flags & 1) ((float*)Yv)[off] += v;
          else ((float*)Yv)[off] = v;
        }
      }
    }
  }
}

// ---------------- combine split-K partials: out = (sum_s SP[s]) + bias ----------------
__global__ __launch_bounds__(256) void k_combine(const float* __restrict__ SP,
                                                 const float* __restrict__ bias,
                                                 void* __restrict__ out,
                                                 long MOC, int lgOC, int nsplit, int flags) {
  long idx = (long)blockIdx.x * 256 + threadIdx.x;
  if (idx >= MOC) return;
  float v = bias[idx & ((1 << lgOC) - 1)];
  for (int s = 0; s < nsplit; ++s) v += SP[s * MOC + idx];
  if (flags & 2) v = fmaxf(v, 0.f);
  if (flags & 4) ((u16*)out)[idx] = f2bf(v);
  else if (flags & 1) ((float*)out)[idx] += v;
  else ((float*)out)[idx] = v;
}

// ---------------- TLG windowed cross attention: 8q x 8k per (window, head), bf16 ----------------
__global__ __launch_bounds__(256) void k_tlg_attn(const u16* __restrict__ Q,
                                                  const u16* __restrict__ K,
                                                  const u16* __restrict__ V,
                                                  u16* __restrict__ Y) {
  int gw = blockIdx.x * 4 + (threadIdx.x >> 6);
  int lane = threadIdx.x & 63;
  int head = gw & 7;
  int win = gw >> 3;
  int wB = win & 7, hB = (win >> 3) & 7, dB = (win >> 6) & 7, l = win >> 9;
  int i = lane >> 3, j = lane & 7;
  int nq = (l << 12) | ((dB * 2 + (i >> 2)) << 8) | ((hB * 2 + ((i >> 1) & 1)) << 4) |
           (wB * 2 + (i & 1));
  int lk = l ^ 2;
  int nk = (lk << 12) | ((dB * 2 + (j >> 2)) << 8) | ((hB * 2 + ((j >> 1) & 1)) << 4) |
           (wB * 2 + (j & 1));
  int hoff = head * 16;
  const u16* qp = Q + (long)nq * 128 + hoff;
  const u16* kp = K + (long)nk * 128 + hoff;
  float s = 0.f;
#pragma unroll
  for (int t = 0; t < 16; t += 4) {
    float4 a = load4bf(qp + t);
    float4 b = load4bf(kp + t);
    s += a.x * b.x + a.y * b.y + a.z * b.z + a.w * b.w;
  }
  s *= 0.25f;
  float mx = s;
#pragma unroll
  for (int o = 1; o < 8; o <<= 1) mx = fmaxf(mx, __shfl_xor(mx, o));
  float e = __expf(s - mx);
  float sum = e;
#pragma unroll
  for (int o = 1; o < 8; o <<= 1) sum += __shfl_xor(sum, o);
  float p = e / sum;
  const u16* vp = V + (long)nk * 128 + hoff;
  float y[16];
#pragma unroll
  for (int t = 0; t < 16; t += 4) {
    float4 vv = load4bf(vp + t);
    y[t] = p * vv.x; y[t + 1] = p * vv.y; y[t + 2] = p * vv.z; y[t + 3] = p * vv.w;
  }
#pragma unroll
  for (int o = 1; o < 8; o <<= 1) {
#pragma unroll
    for (int t = 0; t < 16; ++t) y[t] += __shfl_xor(y[t], o);
  }
  if (j == 0) {
    u16* yp = Y + (long)nq * 128 + hoff;
    u16 tmp[16];
#pragma unroll
    for (int t = 0; t < 16; ++t) tmp[t] = f2bf(y[t]);
    *(uint4*)(yp) = *(uint4*)tmp;
    *(uint4*)(yp + 8) = *(uint4*)(tmp + 8);
  }
}

// ---------------- SLG K/V repack for flash attn ----------------
__global__ __launch_bounds__(256) void k_pack_kh(const u16* __restrict__ Kin,
                                                 u16* __restrict__ Kh) {
  int idx = blockIdx.x * 256 + threadIdx.x;
  if (idx >= 8 * 1032 * 16) return;
  int d = idx & 15;
  int r = idx >> 4;
  int k = r % 1032, h = r / 1032;
  Kh[idx] = Kin[k * 128 + h * 16 + d];
}
__global__ __launch_bounds__(256) void k_pack_vt(const u16* __restrict__ Vin,
                                                 u16* __restrict__ Vt) {
  int idx = blockIdx.x * 256 + threadIdx.x;
  if (idx >= 8 * 16 * 1032) return;
  int k = idx % 1032;
  int r = idx / 1032;
  int d = r & 15, h = r >> 4;
  Vt[idx] = Vin[k * 128 + h * 16 + d];
}

// ---------------- SLG MFMA flash attention ----------------
__global__ __launch_bounds__(256) void k_slg_flash(const u16* __restrict__ Q,
                                                   const u16* __restrict__ Kh,
                                                   const u16* __restrict__ Vt,
                                                   u16* __restrict__ Y) {
  constexpr int NK = 1032;
  constexpr int NTILE = 17;
  __shared__ __align__(16) u16 Ks[64 * 24];
  __shared__ __align__(16) u16 Vs[16 * 72];
  __shared__ __align__(16) u16 Ps[4][16 * 72];
  int tid = threadIdx.x;
  int wave = tid >> 6, lane = tid & 63;
  int quad = lane >> 4, l15 = lane & 15;
  int h = blockIdx.x & 7;
  int q0 = (blockIdx.x >> 3) * 64 + wave * 16;

  const bf16x8 Zb = {0, 0, 0, 0, 0, 0, 0, 0};
  bf16x8 qf = Zb;
  if (quad < 2) qf = *(const bf16x8*)(Q + (long)(q0 + l15) * 128 + h * 16 + quad * 8);

  const u16* Kbase = Kh + (long)h * NK * 16;
  const u16* Vbase = Vt + (long)h * 16 * NK;

  float mrow[4], lrow[4];
  f32x4 oacc = {0.f, 0.f, 0.f, 0.f};
#pragma unroll
  for (int r = 0; r < 4; ++r) { mrow[r] = -1e30f; lrow[r] = 0.f; }

  int skey = tid >> 2, sch = (tid & 3) * 4;
  int svd = tid >> 4, svc = (tid & 15) * 4;

  for (int t = 0; t < NTILE; ++t) {
    int k0 = t * 64;
    __syncthreads();
    {
      short4 v = {0, 0, 0, 0};
      int key = k0 + skey;
      if (key < NK) v = *(const short4*)(Kbase + key * 16 + sch);
      *(short4*)&Ks[skey * 24 + sch] = v;
    }
    {
      short4 v = {0, 0, 0, 0};
      int colb = k0 + svc;
      if (colb < NK) v = *(const short4*)(Vbase + svd * NK + colb);
      *(short4*)&Vs[svd * 72 + svc] = v;
    }
    __syncthreads();

    f32x4 s[4];
#pragma unroll
    for (int sub = 0; sub < 4; ++sub) {
      bf16x8 b = Zb;
      if (quad < 2) b = *(const bf16x8*)&Ks[(sub * 16 + l15) * 24 + quad * 8];
      f32x4 zero = {0.f, 0.f, 0.f, 0.f};
      s[sub] = __builtin_amdgcn_mfma_f32_16x16x32_bf16(qf, b, zero, 0, 0, 0);
    }
    float pv[4][4];
    float tmax[4] = {-1e30f, -1e30f, -1e30f, -1e30f};
#pragma unroll
    for (int sub = 0; sub < 4; ++sub) {
      int key = k0 + sub * 16 + l15;
      bool valid = key < NK;
#pragma unroll
      for (int r = 0; r < 4; ++r) {
        float sv = valid ? s[sub][r] * 0.25f : -1e30f;
        pv[sub][r] = sv;
        tmax[r] = fmaxf(tmax[r], sv);
      }
    }
#pragma unroll
    for (int o = 1; o < 16; o <<= 1)
#pragma unroll
      for (int r = 0; r < 4; ++r) tmax[r] = fmaxf(tmax[r], __shfl_xor(tmax[r], o));

    float al[4], tsum[4] = {0.f, 0.f, 0.f, 0.f};
#pragma unroll
    for (int r = 0; r < 4; ++r) {
      float mn = fmaxf(mrow[r], tmax[r]);
      al[r] = __expf(mrow[r] - mn);
      mrow[r] = mn;
    }
#pragma unroll
    for (int sub = 0; sub < 4; ++sub)
#pragma unroll
      for (int r = 0; r < 4; ++r) {
        float pe = __expf(pv[sub][r] - mrow[r]);
        tsum[r] += pe;
        Ps[wave][(quad * 4 + r) * 72 + sub * 16 + l15] = f2bf(pe);
      }
#pragma unroll
    for (int o = 1; o < 16; o <<= 1)
#pragma unroll
      for (int r = 0; r < 4; ++r) tsum[r] += __shfl_xor(tsum[r], o);
#pragma unroll
    for (int r = 0; r < 4; ++r) {
      lrow[r] = lrow[r] * al[r] + tsum[r];
      oacc[r] *= al[r];
    }
    bf16x8 pa0 = *(const bf16x8*)&Ps[wave][l15 * 72 + quad * 8];
    bf16x8 pa1 = *(const bf16x8*)&Ps[wave][l15 * 72 + 32 + quad * 8];
    bf16x8 vb0 = *(const bf16x8*)&Vs[l15 * 72 + quad * 8];
    bf16x8 vb1 = *(const bf16x8*)&Vs[l15 * 72 + 32 + quad * 8];
    oacc = __builtin_amdgcn_mfma_f32_16x16x32_bf16(pa0, vb0, oacc, 0, 0, 0);
    oacc = __builtin_amdgcn_mfma_f32_16x16x32_bf16(pa1, vb1, oacc, 0, 0, 0);
  }

#pragma unroll
  for (int r = 0; r < 4; ++r) {
    float inv = 1.0f / lrow[r];
    Y[(long)(q0 + quad * 4 + r) * 128 + h * 16 + l15] = f2bf(oacc[r] * inv);
  }
}

static inline int ilg(int v) { int r = 0; while ((1 << r) < v) ++r; return r; }

extern "C" void kernel_launch(void* const* d_in, const int* in_sizes, int n_in,
                              void* d_out, int out_size, void* d_ws, size_t ws_size,
                              hipStream_t stream) {
  (void)in_sizes; (void)n_in; (void)out_size; (void)ws_size;
  const float* x    = (const float*)d_in[0];
  const float* n1_w = (const float*)d_in[1];  const float* n1_b = (const float*)d_in[2];
  const float* n2_w = (const float*)d_in[3];  const float* n2_b = (const float*)d_in[4];
  const float* n3_w = (const float*)d_in[5];  const float* n3_b = (const float*)d_in[6];
  const float* sn_w = (const float*)d_in[7];  const float* sn_b = (const float*)d_in[8];
  const float* tq_w = (const float*)d_in[9];  const float* tq_b = (const float*)d_in[10];
  const float* tk_w = (const float*)d_in[11]; const float* tk_b = (const float*)d_in[12];
  const float* tv_w = (const float*)d_in[13]; const float* tv_b = (const float*)d_in[14];
  const float* tp_w = (const float*)d_in[15]; const float* tp_b = (const float*)d_in[16];
  const float* sq_w = (const float*)d_in[17]; const float* sq_b = (const float*)d_in[18];
  const float* sk_w = (const float*)d_in[19]; const float* sk_b = (const float*)d_in[20];
  const float* sv_w = (const float*)d_in[21]; const float* sv_b = (const float*)d_in[22];
  const float* sp_w = (const float*)d_in[23]; const float* sp_b = (const float*)d_in[24];
  const float* sf_w = (const float*)d_in[25]; const float* sf_b = (const float*)d_in[26];
  const float* sc_w = (const float*)d_in[27]; const float* sc_b = (const float*)d_in[28];
  const float* m1_w = (const float*)d_in[29]; const float* m1_b = (const float*)d_in[30];
  const float* m2_w = (const float*)d_in[31]; const float* m2_b = (const float*)d_in[32];

  char* p = (char*)d_ws;
  auto alloc = [&](size_t bytes) { char* r = p; p += (bytes + 255) & ~(size_t)255; return r; };
  const long N = 16384;
  float* X0 = (float*)alloc(N * 128 * 4);
  u16* XN = (u16*)alloc(N * 128 * 2);
  u16* Qb = (u16*)alloc(N * 128 * 2);
  u16* Kb = (u16*)alloc(N * 128 * 2);
  u16* Vb = (u16*)alloc(N * 128 * 2);
  u16* Yb = (u16*)alloc(N * 128 * 2);
  u16* H  = (u16*)alloc(N * 512 * 2);
  u16* XC = (u16*)alloc(8 * 128 * 2);
  u16* XF = (u16*)alloc(1024 * 128 * 2);
  float* Kf = (float*)alloc(1032 * 128 * 4);
  float* Vf = (float*)alloc(1032 * 128 * 4);
  u16* Kh = (u16*)alloc(8 * 1032 * 16 * 2);
  u16* Vt = (u16*)alloc(8 * 16 * 1032 * 2);
  float* SPb = (float*)alloc(4L * N * 128 * 4);  // split-K partials
  u16* ZPb = (u16*)alloc(256);                    // zero page for masked gather rows
  u16* tq2 = (u16*)alloc(49152 * 2);  u16* tk2 = (u16*)alloc(49152 * 2);
  u16* tv2 = (u16*)alloc(49152 * 2);  u16* tp2 = (u16*)alloc(49152 * 2);
  u16* sq2 = (u16*)alloc(442368 * 2); u16* sk2 = (u16*)alloc(442368 * 2);
  u16* sv2 = (u16*)alloc(442368 * 2); u16* sp2 = (u16*)alloc(442368 * 2);
  u16* sf2 = (u16*)alloc(442368 * 2); u16* sc2 = (u16*)alloc(442368 * 2);
  u16* m12 = (u16*)alloc(5308416L * 2);
  u16* m22 = (u16*)alloc(5308416L * 2);

  k_zeropage<<<1, 128, 0, stream>>>(ZPb);

  auto rp = [&](const float* W, u16* Wb, int OC, int IC, int NT) {
    long tot = (long)OC * IC * NT;
    k_repack_bf<<<(int)((tot + 255) / 256), 256, 0, stream>>>(W, Wb, ilg(OC), ilg(IC), NT, tot);
  };
  rp(tq_w, tq2, 128, 128, 3);  rp(tk_w, tk2, 128, 128, 3);
  rp(tv_w, tv2, 128, 128, 3);  rp(tp_w, tp2, 128, 128, 3);
  rp(sq_w, sq2, 128, 128, 27); rp(sk_w, sk2, 128, 128, 27);
  rp(sv_w, sv2, 128, 128, 27); rp(sp_w, sp2, 128, 128, 27);
  rp(sf_w, sf2, 128, 128, 27); rp(sc_w, sc2, 128, 128, 27);
  rp(m1_w, m12, 512, 128, 81); rp(m2_w, m22, 128, 512, 81);

  // small convs (M not multiple of 128 or tiny grids)
  auto conv = [&](const u16* Xp, const u16* Wp, const float* Bp, void* Yp,
                  int M, int IC, int OC, int mode, int NT,
                  int Do, int Ho, int Wo, int Li, int Di, int Hi, int Wi,
                  int sL, int sD, int sH, int sW, int flags) {
    int lgWo = ilg(Wo), lgHo = ilg(Ho), lgDo = ilg(Do);
    int lgWi = ilg(Wi), lgHi = ilg(Hi), lgDi = ilg(Di);
    dim3 g((M + 63) / 64, OC / 64);
    k_conv_mfma<<<g, 256, 0, stream>>>(Xp, Wp, Bp, Yp, M, IC, OC, mode, NT,
                                       lgWo, lgHo, lgDo, lgWi, lgHi, lgDi,
                                       Li, Di, Hi, Wi, sL, sD, sH, sW, flags);
  };
  // big GEMMs on full 16384-token grid -> global_load_lds kernel (+ optional split-K)
  auto conv_gl = [&](const u16* Xp, const u16* Wp, const float* Bp, void* Yp,
                     int M, int IC, int OC, int mode, int NT, int nsplit, int flags) {
    dim3 g(M / 128, OC / 128, nsplit);
    k_conv_gl<<<g, 256, 0, stream>>>(Xp, Wp, Bp, Yp, SPb, ZPb, M, IC, OC, mode, NT, nsplit,
                                     4, 4, 4, 4, 4, 4, 4, 16, 16, 16, 1, 1, 1, 1, flags);
    if (nsplit > 1) {
      long MOC = (long)M * OC;
      k_combine<<<(int)((MOC + 255) / 256), 256, 0, stream>>>(SPb, Bp, Yp, MOC, ilg(OC),
                                                              nsplit, flags);
    }
  };

  k_transpose_in<<<8192, 256, 0, stream>>>(x, X0);

  // ---- TLG branch ----
  k_ln_f2b<<<4096, 256, 0, stream>>>(X0, n1_w, n1_b, XN, 16384);
  conv_gl(XN, tq2, tq_b, Qb, 16384, 128, 128, 0, 3, 3, 4);
  conv_gl(XN, tk2, tk_b, Kb, 16384, 128, 128, 0, 3, 3, 4);
  conv_gl(XN, tv2, tv_b, Vb, 16384, 128, 128, 0, 3, 3, 4);
  k_tlg_attn<<<4096, 256, 0, stream>>>(Qb, Kb, Vb, Yb);
  conv_gl(Yb, tp2, tp_b, X0, 16384, 128, 128, 0, 3, 3, 1);

  // ---- SLG branch ----
  k_ln_f2b<<<4096, 256, 0, stream>>>(X0, n2_w, n2_b, XN, 16384);
  conv_gl(XN, sq2, sq_b, Qb, 16384, 128, 128, 1, 27, 4, 4);
  conv(XN, sc2, sc_b, XC, 8,    128, 128, 1, 27, 2, 2, 2,   4, 16, 16, 16, 4, 8, 8, 8, 4);
  conv(XN, sf2, sf_b, XF, 1024, 128, 128, 1, 27, 8, 8, 8,   4, 16, 16, 16, 2, 2, 2, 2, 4);
  conv(XC, sk2, sk_b, Kf,            8,    128, 128, 1, 27, 2, 2, 2, 1, 2, 2, 2, 1, 1, 1, 1, 0);
  conv(XF, sk2, sk_b, Kf + 8 * 128,  1024, 128, 128, 1, 27, 8, 8, 8, 2, 8, 8, 8, 1, 1, 1, 1, 0);
  conv(XC, sv2, sv_b, Vf,            8,    128, 128, 1, 27, 2, 2, 2, 1, 2, 2, 2, 1, 1, 1, 1, 0);
  conv(XF, sv2, sv_b, Vf + 8 * 128,  1024, 128, 128, 1, 27, 8, 8, 8, 2, 8, 8, 8, 1, 1, 1, 1, 0);
  k_ln_f2b<<<258, 256, 0, stream>>>(Kf, sn_w, sn_b, Kb, 1032);
  k_ln_f2b<<<258, 256, 0, stream>>>(Vf, sn_w, sn_b, Vb, 1032);
  k_pack_kh<<<516, 256, 0, stream>>>(Kb, Kh);
  k_pack_vt<<<516, 256, 0, stream>>>(Vb, Vt);
  k_slg_flash<<<2048, 256, 0, stream>>>(Qb, Kh, Vt, Yb);
  conv_gl(Yb, sp2, sp_b, X0, 16384, 128, 128, 1, 27, 4, 1);

  // ---- MLP branch ----
  k_ln_f2b<<<4096, 256, 0, stream>>>(X0, n3_w, n3_b, XN, 16384);
  conv_gl(XN, m12, m1_b, H, 16384, 128, 512, 2, 81, 1, 6);
  conv_gl(H, m22, m2_b, X0, 16384, 512, 128, 2, 81, 4, 1);

  k_transpose_out<<<8192, 256, 0, stream>>>(X0, (float*)d_out);
}